// Round 1
// 8127.499 us; speedup vs baseline: 1.6252x; 1.6252x over previous
//
#include <hip/hip_runtime.h>
#include <hip/hip_bf16.h>

typedef unsigned short u16;
typedef unsigned int   u32;
typedef unsigned long long u64;

typedef __attribute__((ext_vector_type(8))) short bf16x8;  // 8 x bf16 (4 VGPR) MFMA A/B frag
typedef __attribute__((ext_vector_type(4))) float f32x4;   // MFMA C/D frag
typedef __attribute__((ext_vector_type(4))) u32   u32x4;

#define L2E 1.44269504088896340736f

__device__ __forceinline__ float bf2f(u16 u){ union{u32 i; float f;} v; v.i=((u32)u)<<16; return v.f; }
__device__ __forceinline__ u16  f2bf(float f){ union{float f; u32 i;} v; v.f=f; u32 u=v.i; return (u16)((u + 0x7fffu + ((u>>16)&1u))>>16); }
__device__ __forceinline__ u32  packbf(float a,float b){ return (u32)f2bf(a) | ((u32)f2bf(b)<<16); }
__device__ __forceinline__ float tanh_f(float x){
  float cx = fminf(fmaxf(x,-15.f),15.f);
  float e  = __builtin_amdgcn_exp2f(cx*(2.f*L2E));
  return (e-1.f)*__builtin_amdgcn_rcpf(e+1.f);
}
__device__ __forceinline__ float sig_f(float x){
  float cx = fminf(fmaxf(x,-30.f),30.f);
  float e  = __builtin_amdgcn_exp2f(-cx*L2E);
  return __builtin_amdgcn_rcpf(1.f+e);
}
// Cross-XCD coherent accesses: relaxed agent-scope atomics (bypass per-XCD caches; L3 = coherence point).
__device__ __forceinline__ u64   lda2(const u64* p){ return __hip_atomic_load((u64*)p, __ATOMIC_RELAXED, __HIP_MEMORY_SCOPE_AGENT); }
__device__ __forceinline__ void  sta(u32* p, u32 v){ __hip_atomic_store(p, v, __ATOMIC_RELAXED, __HIP_MEMORY_SCOPE_AGENT); }
__device__ __forceinline__ void  sta2(u64* p, u64 v){ __hip_atomic_store(p, v, __ATOMIC_RELAXED, __HIP_MEMORY_SCOPE_AGENT); }
__device__ __forceinline__ bf16x8 as_bf8(u32x4 w){ union{u32x4 u; bf16x8 b;} c; c.u=w; return c.b; }
// fragment-major address for an h/att element pair: batch r, u32-col c (h element pair 2c,2c+1)
__device__ __forceinline__ int frag_a(int r, int c){
  return ((c>>4)*2 + (r>>4))*256 + (((c>>2)&3))*64 + ((r&15))*4 + (c&3);
}

// ---------------- prep: W_ih/W_hh (f32) -> fragment-major bf16 Wf [gs][nt<4][ks<32][lane][8] ----------------
__global__ void k_prep_w(const float* __restrict__ W_ih, const float* __restrict__ W_hh, u16* __restrict__ Wf){
  int idx = blockIdx.x*256 + threadIdx.x;        // 2,097,152
  int j    = idx & 7;
  int lane = (idx >> 3) & 63;
  int ks   = (idx >> 9) & 31;
  int nt   = (idx >> 14) & 3;
  int gs   = idx >> 16;                          // < 32
  int grow = nt*512 + gs*16 + (lane & 15);       // global gate row (nt = gate i/f/g/o)
  int k    = ks*32 + ((lane >> 4) & 3)*8 + j;    // 0..1023: [att 512 | h 512]
  float v = (k < 512) ? W_ih[grow*517 + k] : W_hh[grow*512 + (k - 512)];
  Wf[idx] = f2bf(v);
}
// ---------------- prep: K_conv (f32) -> fragment-major bf16 Kf [tap][nt<16][ks<16][lane][8] ----------------
__global__ void k_prep_kf(const float* __restrict__ Kc, u16* __restrict__ Kf){
  int idx = blockIdx.x*256 + threadIdx.x;        // 1,179,648
  int j    = idx & 7;
  int lane = (idx >> 3) & 63;
  int ks   = (idx >> 9) & 15;
  int nt   = (idx >> 13) & 15;
  int tap  = idx >> 17;                          // < 9
  int oc = nt*16 + (lane & 15);
  int ic = ks*32 + ((lane >> 4) & 3)*8 + j;
  Kf[idx] = f2bf(Kc[(oc*512 + ic)*9 + tap]);
}
// ---------------- prep: W_conv_h (f32) e-slices -> fragment-major WcF [gs][ks<16][lane][4 u32] ----------------
__global__ void k_prep_wcf(const float* __restrict__ Wch, u32* __restrict__ WcF){
  int idx = blockIdx.x*256 + threadIdx.x;        // 131,072 u32
  int j2 = idx & 3, l = (idx>>2) & 63, ks = (idx>>8) & 15, gs = idx >> 12;
  int c0 = l & 15, q = l >> 4;
  u32 v = 0u;
  if (c0 < 8){
    int row = gs*8 + c0;
    int kk  = (ks*16 + q*4 + j2)*2;              // bf16-pair base within row of 512
    v = packbf(Wch[row*512 + kk], Wch[row*512 + kk + 1]);
  }
  WcF[idx] = v;
}
// ---------------- prep: W_fc_params (f32) -> fragment-major bf16 WpF [ntile<8][ks<16][lane][8] ----------------
__global__ void k_prep_wp(const float* __restrict__ Wp, u16* __restrict__ WpF){
  int idx = blockIdx.x*256 + threadIdx.x;        // 65,536
  int j = idx & 7, lane = (idx>>3) & 63, ks = (idx>>9) & 15, ntile = idx >> 13;
  int n = ntile*16 + (lane & 15);
  int k = ks*32 + (lane >> 4)*8 + j;
  WpF[idx] = (n < 123) ? f2bf(Wp[n*512 + k]) : (u16)0;
}
// ---------------- init: hc = tanh(z @ W_fc_hc^T + b) -> h_pack (fragment-major bf16 pairs), c_ws (f32) ----------------
__global__ void k_hc(const float* __restrict__ z, const float* __restrict__ Wfc, const float* __restrict__ bfc,
                     u32* __restrict__ h_pack, float* __restrict__ c_ws){
  __shared__ float zl[128];
  int b = blockIdx.x, t = threadIdx.x;
  if (t < 128) zl[t] = z[b*128 + t];
  __syncthreads();
  float acc[4];
  #pragma unroll
  for (int i=0;i<4;i++){
    int n = 4*t + i;
    const float* row = Wfc + n*128;
    float a = 0.f;
    #pragma unroll 8
    for (int k2=0;k2<128;k2++) a += row[k2]*zl[k2];
    acc[i] = tanh_f(a + bfc[n]);
  }
  int bg = b >> 5, r = b & 31;
  if (t < 128){
    h_pack[bg*8192 + frag_a(r, 2*t)]   = packbf(acc[0], acc[1]);
    h_pack[bg*8192 + frag_a(r, 2*t+1)] = packbf(acc[2], acc[3]);
  } else {
    int base = 4*t - 512;
    #pragma unroll
    for (int i=0;i<4;i++) c_ws[b*512 + base + i] = acc[i];
  }
}
// ---------------- conv 3x3 SAME (f32 in, bf16 out) + bf16 backbone copy ----------------
__device__ __forceinline__ int xt_addr(int p, int chunk){ return p*512 + ((chunk ^ (p & 7))<<3); } // XOR-swizzled LDS
__global__ __launch_bounds__(256) void k_conv(const float* __restrict__ bb, const u16* __restrict__ Kf,
                       const float* __restrict__ bcf, u16* __restrict__ x_em, u16* __restrict__ bb_bf){
  __shared__ u16 xt[64*512];  // exactly 64KB, swizzled [p][ic]
  int b = blockIdx.x, t = threadIdx.x;
  const float* src = bb + (size_t)b*512*64;
  u16* dstc = bb_bf + (size_t)b*512*64;
  for (int i=0;i<128;i++){
    int idx = i*256 + t;
    int ic = idx >> 6, p = idx & 63;
    u16 v = f2bf(src[idx]);
    xt[xt_addr(p, ic>>3) + (ic&7)] = v;
    dstc[idx] = v;                         // bf16 copy, same [b][c][p] layout
  }
  __syncthreads();
  int wv = t >> 6, l = t & 63, c0 = l & 15, q = l >> 4;
  f32x4 acc[4][4];
  #pragma unroll
  for (int a=0;a<4;a++)
    #pragma unroll
    for (int bq=0;bq<4;bq++) acc[a][bq] = (f32x4)0.f;
  for (int tap=0; tap<9; ++tap){
    int ty = tap/3 - 1, tx = tap%3 - 1;
    for (int ks=0; ks<16; ++ks){
      bf16x8 afr[4];
      #pragma unroll
      for (int mt=0; mt<4; ++mt){
        int p = mt*16 + c0;
        int py = (p >> 3) + ty, px = (p & 7) + tx;
        if ((unsigned)py < 8u && (unsigned)px < 8u){
          afr[mt] = *(const bf16x8*)(&xt[xt_addr(py*8+px, ks*4 + q)]);
        } else {
          afr[mt] = (bf16x8)0;
        }
      }
      #pragma unroll
      for (int ni=0; ni<4; ++ni){
        int nt = wv*4 + ni;
        bf16x8 bfr = as_bf8(*(const u32x4*)(const void*)(Kf + (size_t)((((tap*16 + nt)*16 + ks)*64) + l)*8));
        #pragma unroll
        for (int mt=0; mt<4; ++mt)
          acc[mt][ni] = __builtin_amdgcn_mfma_f32_16x16x32_bf16(afr[mt], bfr, acc[mt][ni], 0,0,0);
      }
    }
  }
  #pragma unroll
  for (int ni=0; ni<4; ++ni){
    int e = (wv*4+ni)*16 + c0;
    float bias = bcf[e];
    #pragma unroll
    for (int mt=0; mt<4; ++mt)
      #pragma unroll
      for (int r=0;r<4;r++){
        int p = mt*16 + q*4 + r;
        x_em[(size_t)(b*256 + e)*64 + p] = f2bf(acc[mt][ni][r] + bias);
      }
  }
}

// ---------------- group barrier: RELAXED flag store; ordering comes from the vmcnt(0) drain that
// __syncthreads performs (all waves' agent-scope write-through stores are acked at the coherence
// point before any wave passes s_barrier, hence before the flag store issues).
// NOTE: deliberately NOT __ATOMIC_RELEASE — agent-scope release on gfx950 emits buffer_wbl2 (full
// per-XCD L2 writeback scan) which serialized ~96x/step/XCD and dominated runtime. ----------------
__device__ __forceinline__ void gbar(u32* slots, int bg, int gs, int t, u32 seq){
  __syncthreads();   // s_waitcnt vmcnt(0) before s_barrier: all waves' agent-scope stores at coherence point
  if (t == 0) __hip_atomic_store(&slots[(bg*32 + gs)*16], seq, __ATOMIC_RELAXED, __HIP_MEMORY_SCOPE_AGENT);
  if (t < 32){
    while (__hip_atomic_load(&slots[(bg*32 + t)*16], __ATOMIC_RELAXED, __HIP_MEMORY_SCOPE_AGENT) < seq)
      __builtin_amdgcn_s_sleep(1);
  }
  __atomic_signal_fence(__ATOMIC_ACQUIRE);   // compiler barrier only: data loads stay after the spin
  __syncthreads();
}

// ---------------- head postprocess for one batch row (32-col superblock gs); nontemporal f32 out ----------------
__device__ __forceinline__ void head_post(const float* yL, const float* __restrict__ bp,
                                          float* __restrict__ out, int gs, int bg, int bL2, int step){
  const int CH = 1315840;          // 65792*20
  const int PEN = 7895040;         // 6*CH
  int rr = (bg*32 + bL2)*257 + step;
  float m = -1e30f, rs = 0.f;
  if (gs == 0){
    float su = 0.f;
    #pragma unroll 1
    for (int c=3;c<23;c++){ float v = yL[bL2*33 + c] + bp[c]; m = fmaxf(m, v); }
    #pragma unroll 1
    for (int c=3;c<23;c++){ float v = yL[bL2*33 + c] + bp[c]; su += __builtin_amdgcn_exp2f((v-m)*L2E); }
    rs = __builtin_amdgcn_rcpf(su);
  }
  #pragma unroll 1
  for (int c2=0;c2<32;c2++){
    int col = gs*32 + c2;
    if (col >= 123) break;
    float v = yL[bL2*33 + c2] + bp[col];
    float tv; int oidx;
    if (col < 3){ tv = v; oidx = PEN + rr*3 + col; }
    else {
      int j = col - 3, ch = j/20, jj = j - ch*20;
      if (ch == 0)      tv = __builtin_amdgcn_exp2f((v-m)*L2E)*rs;
      else if (ch <= 2) tv = v;
      else if (ch <= 4) tv = __builtin_amdgcn_exp2f(v*L2E);
      else              tv = tanh_f(v);
      oidx = ch*CH + rr*20 + jj;
    }
    __builtin_nontemporal_store(tv, &out[oidx]);
  }
}

// ---------------- persistent RNN scan + fused head: 8 bg-groups x 32 gs-blocks ----------------
__global__ __launch_bounds__(256) void k_rnn(
    const u16* __restrict__ bb_bf, const float* __restrict__ sketch,
    const float* __restrict__ b_ch, const float* __restrict__ Watt,
    const float* __restrict__ W_ih, const float* __restrict__ b_ih, const float* __restrict__ b_hh,
    const u16* __restrict__ x_em, const u16* __restrict__ Wf, const u32* __restrict__ WcF,
    const u16* __restrict__ WpF, const float* __restrict__ bp,
    u32* __restrict__ h_pack, u32* __restrict__ att_pack, float* __restrict__ spart,
    const float* __restrict__ c_ws, u32* __restrict__ slots, float* __restrict__ outp)
{
  __shared__ u32 hF[8192];        // 32KB: h fragments [tile<32][lane][4 u32], tile = ks2*2 + (r>>4)
  __shared__ u32 xaH[4096];       // 16KB: att fragments for a 16-batch half; also spart staging / A2 reduce scratch
  __shared__ float gemL[32*8];
  __shared__ float alphaL[64];
  __shared__ float ptL[32*8];
  __shared__ float w5L[64*8];
  __shared__ float biasL[64];
  __shared__ float wattL[8];
  __shared__ float yL[32*33];     // head y staging (4.2KB)
  float* gbufL = (float*)xaH;

  int t = threadIdx.x;
  int bg = blockIdx.x >> 5, gs = blockIdx.x & 31;
  int E0 = gs*8;
  int lane = t & 63, wv = t >> 6;
  int c0 = lane & 15, q = lane >> 4;

  // one-time staging
  if (t < 8) wattL[t] = Watt[E0 + t];
  if (t < 64){
    int grow = (t >> 4)*512 + gs*16 + (t & 15);
    biasL[t] = b_ih[grow] + b_hh[grow];
    #pragma unroll
    for (int d=0; d<5; ++d) w5L[t*8+d] = W_ih[grow*517 + 512 + d];
  }
  int bL = t & 31, hp = t >> 5;              // LSTM role
  int gb_l = bg*32 + bL;
  float c0r = c_ws[gb_l*512 + gs*16 + 2*hp];
  float c1r = c_ws[gb_l*512 + gs*16 + 2*hp + 1];
  int a1_b = t >> 3, a1_e = t & 7;           // A1 score role
  int gb_sc = bg*32 + a1_b;
  int ba = bg*32 + gs;                       // A2 batch
  float bchL = (c0 < 8) ? b_ch[E0 + c0] : 0.f;
  const u16* wb = Wf + (size_t)(((gs*4 + wv)*32)*64 + lane)*8;
  const u32* wcf = WcF + (size_t)gs*4096;    // slice stride = 16*64*4 = 4096 u32
  const u64* hsrc = (const u64*)(h_pack + (size_t)bg*8192);
  u64* hdst = (u64*)hF;
  const u64* asrc = (const u64*)(att_pack + (size_t)bg*8192);
  u64* adst = (u64*)xaH;
  int hpub_a = frag_a(bL, gs*8 + hp);        // h publish slot (fragment-major)
  int apub_a = ((gs>>4)<<12) + ((t>>4)<<8) + (((t>>2)&3)<<6) + ((gs&15)<<2) + (t&3);  // att publish slot
  u32 seq = 0;
  __syncthreads();

  #pragma clang loop unroll(disable)
  for (int ts=0; ts<257; ++ts){
    // ======== stage h (fragment-major memcpy: coalesced ull atomics -> dense ds_write_b64) + pt ========
    #pragma unroll
    for (int k=0;k<16;k++){
      int idx = k*256 + t;
      hdst[idx] = lda2(&hsrc[idx]);
    }
    if (t < 32){
      float p0,p1,p2,p3,p4;
      if (ts == 0){ p0=0.f;p1=0.f;p2=1.f;p3=0.f;p4=0.f; }
      else {
        const float* sp = sketch + ((size_t)(ts-1)*256 + (bg*32 + t))*5;
        p0=sp[0]; p1=sp[1]; p2=sp[2]; p3=sp[3]; p4=sp[4];
      }
      ptL[t*8+0]=p0; ptL[t*8+1]=p1; ptL[t*8+2]=p2; ptL[t*8+3]=p3; ptL[t*8+4]=p4;
    }
    __syncthreads();
    // ======== C: fused head for step ts-1 (hF = h_{ts-1}); blocks gs<4 only ========
    if (gs < 4 && ts > 0){
      int mh = wv & 1, nt2 = wv >> 1;
      f32x4 ya = (f32x4)0.f;
      #pragma unroll 4
      for (int ks=0; ks<16; ++ks){
        bf16x8 bw = as_bf8(*(const u32x4*)(const void*)(WpF + (size_t)((((gs*2+nt2)*16 + ks)*64) + lane)*8));
        bf16x8 ah = *(const bf16x8*)(&hF[(ks*2 + mh)*256 + lane*4]);
        ya = __builtin_amdgcn_mfma_f32_16x16x32_bf16(ah, bw, ya, 0,0,0);
      }
      #pragma unroll
      for (int r=0;r<4;r++) yL[(mh*16 + q*4 + r)*33 + nt2*16 + c0] = ya[r];
      __syncthreads();
      if (wv == 3 && lane < 32) head_post(yL, bp, outp, gs, bg, lane, ts-1);
    }
    // ======== A1: g_em slice via MFMA (wave0); tanh partial scores (all) ========
    if (wv == 0){  // g_em = h @ Wc_slice^T  (M=32, N=8 in a 16-wide tile, K=512)
      f32x4 g0 = (f32x4)0.f, g1 = (f32x4)0.f;
      #pragma unroll 4
      for (int ks2=0; ks2<16; ++ks2){
        bf16x8 bfr = as_bf8(*(const u32x4*)(&wcf[ks2*256 + lane*4]));
        bf16x8 a0 = *(const bf16x8*)(&hF[(ks2*2)*256 + lane*4]);
        bf16x8 a1 = *(const bf16x8*)(&hF[(ks2*2+1)*256 + lane*4]);
        g0 = __builtin_amdgcn_mfma_f32_16x16x32_bf16(a0, bfr, g0, 0,0,0);
        g1 = __builtin_amdgcn_mfma_f32_16x16x32_bf16(a1, bfr, g1, 0,0,0);
      }
      if (c0 < 8){
        #pragma unroll
        for (int r=0;r<4;r++){
          gemL[(q*4+r)*8 + c0]      = g0[r] + bchL;
          gemL[(16+q*4+r)*8 + c0]   = g1[r] + bchL;
        }
      }
    }
    __syncthreads();
    {  // partial scores over this block's 8 emb channels; thread=(batch sb, p-octet ps) -> LDS stage
      int sb = a1_b, ps = a1_e;
      float sp[8];
      #pragma unroll
      for (int j=0;j<8;j++) sp[j] = 0.f;
      #pragma unroll
      for (int e=0; e<8; ++e){
        float ge = gemL[sb*8 + e];
        float we = wattL[e];
        const u16* xr = x_em + (size_t)(gb_sc*256 + E0 + e)*64 + ps*8;
        bf16x8 xv = *(const bf16x8*)xr;
        #pragma unroll
        for (int j=0;j<8;j++)
          sp[j] += tanh_f(bf2f((u16)xv[j]) + ge) * we;
      }
      float* stg = (float*)xaH;            // 8KB staging: canonical [sb<32][p<64]
      #pragma unroll
      for (int j=0;j<8;j++) stg[sb*64 + ps*8 + j] = sp[j];
    }
    __syncthreads();
    {  // coalesced u64 publish: wave-instruction covers 512B contiguous -> no HBM write amplification
      const u64* stg64 = (const u64*)xaH;
      u64* dst64 = (u64*)spart + (size_t)(bg*32 + gs)*1024;   // [g2=gs][sb<32][p-pair<32]
      #pragma unroll
      for (int k=0;k<4;k++){
        int idx = k*256 + t;
        sta2(&dst64[idx], stg64[idx]);
      }
    }
    seq++; gbar(slots, bg, gs, t, seq);
    // ======== A2: all-thread coalesced partial reduce, then softmax over 64 p, att for batch ba ========
    {  // thread (p-pair p2 = t&31, quarter gq = t>>5) sums 4 g2 slices; coalesced 256B runs per instr
      int p2 = t & 31, gq = t >> 5;
      const u64* sp64 = (const u64*)spart + (size_t)bg*32768;
      float s0 = 0.f, s1 = 0.f;
      #pragma unroll
      for (int k=0;k<4;k++){
        int g2 = gq*4 + k;
        union{u64 u; float f[2];} c; c.u = lda2(&sp64[(size_t)g2*1024 + gs*32 + p2]);
        s0 += c.f[0]; s1 += c.f[1];
      }
      float* redL = (float*)xaH;           // 2KB reduce scratch [gq<8][p<64]
      redL[gq*64 + 2*p2]     = s0;
      redL[gq*64 + 2*p2 + 1] = s1;
    }
    __syncthreads();
    if (t < 64){
      const float* redL = (const float*)xaH;
      float s = 0.f;
      #pragma unroll
      for (int k=0;k<8;k++) s += redL[k*64 + t];
      float m = s;
      #pragma unroll
      for (int d=1; d<64; d<<=1) m = fmaxf(m, __shfl_xor(m, d, 64));
      float ex = __builtin_amdgcn_exp2f((s - m) * L2E);
      float su = ex;
      #pragma unroll
      for (int d=1; d<64; d<<=1) su += __shfl_xor(su, d, 64);
      alphaL[t] = ex * __builtin_amdgcn_rcpf(su);
    }
    __syncthreads();
    {  // att[c] = sum_p alpha[p]*backbone[ba][c][p]; thread handles c = 2t, 2t+1
      const u16* base = bb_bf + (size_t)(ba*512 + 2*t)*64;
      float a0 = 0.f, a1 = 0.f;
      #pragma unroll
      for (int p8=0; p8<8; ++p8){
        bf16x8 v0 = *(const bf16x8*)(base + p8*8);
        bf16x8 v1 = *(const bf16x8*)(base + 64 + p8*8);
        #pragma unroll
        for (int j=0;j<8;j++){
          float al = alphaL[p8*8+j];
          a0 += al * bf2f((u16)v0[j]);
          a1 += al * bf2f((u16)v1[j]);
        }
      }
      sta(&att_pack[(size_t)bg*8192 + apub_a], packbf(a0, a1));
    }
    seq++; gbar(slots, bg, gs, t, seq);
    // ======== B: gates MFMA (att halves + h), LSTM, publish h ========
    f32x4 acc0 = (f32x4)0.f, acc1 = (f32x4)0.f;
    for (int hb=0; hb<2; ++hb){
      #pragma unroll
      for (int k=0;k<8;k++){
        int idx = k*256 + t;
        adst[idx] = lda2(&asrc[hb*2048 + idx]);
      }
      __syncthreads();
      f32x4 acc = (hb == 0) ? acc0 : acc1;
      #pragma unroll 4
      for (int ks=0; ks<16; ++ks){
        bf16x8 bfr = as_bf8(*(const u32x4*)(const void*)(wb + ks*512));
        bf16x8 af  = *(const bf16x8*)(&xaH[ks*256 + lane*4]);
        acc = __builtin_amdgcn_mfma_f32_16x16x32_bf16(af, bfr, acc, 0,0,0);
      }
      if (hb == 0) acc0 = acc; else acc1 = acc;
      __syncthreads();
    }
    #pragma unroll 4
    for (int ks2=0; ks2<16; ++ks2){
      bf16x8 bfr = as_bf8(*(const u32x4*)(const void*)(wb + (16+ks2)*512));
      bf16x8 a0 = *(const bf16x8*)(&hF[(ks2*2)*256 + lane*4]);
      bf16x8 a1 = *(const bf16x8*)(&hF[(ks2*2+1)*256 + lane*4]);
      acc0 = __builtin_amdgcn_mfma_f32_16x16x32_bf16(a0, bfr, acc0, 0,0,0);
      acc1 = __builtin_amdgcn_mfma_f32_16x16x32_bf16(a1, bfr, acc1, 0,0,0);
    }
    {
      int n = wv*16 + c0;
      #pragma unroll
      for (int r=0;r<4;r++){
        gbufL[n*33 + (q*4 + r)]      = acc0[r];
        gbufL[n*33 + (16 + q*4 + r)] = acc1[r];
      }
    }
    __syncthreads();
    {
      float p0v = ptL[bL*8+0], p1v = ptL[bL*8+1], p2v = ptL[bL*8+2], p3v = ptL[bL*8+3], p4v = ptL[bL*8+4];
      auto gval = [&](int n)->float {
        return gbufL[n*33 + bL] + biasL[n]
             + p0v*w5L[n*8+0] + p1v*w5L[n*8+1] + p2v*w5L[n*8+2] + p3v*w5L[n*8+3] + p4v*w5L[n*8+4];
      };
      float hv0 = 0.f, hv1 = 0.f;
      #pragma unroll
      for (int k2=0;k2<2;k2++){
        int hh = 2*hp + k2;
        float gi = gval(hh), gf = gval(16+hh), gg = gval(32+hh), go = gval(48+hh);
        float cp = k2 ? c1r : c0r;
        float cn = sig_f(gf)*cp + sig_f(gi)*tanh_f(gg);
        float hv = sig_f(go)*tanh_f(cn);
        if (k2){ c1r = cn; hv1 = hv; } else { c0r = cn; hv0 = hv; }
      }
      sta(&h_pack[(size_t)bg*8192 + hpub_a], packbf(hv0, hv1));
    }
    seq++; gbar(slots, bg, gs, t, seq);
  }
  // ======== epilogue: head for step 256 (h_256 now in h_pack) ========
  if (gs < 4){
    #pragma unroll
    for (int k=0;k<16;k++){
      int idx = k*256 + t;
      hdst[idx] = lda2(&hsrc[idx]);
    }
    __syncthreads();
    int mh = wv & 1, nt2 = wv >> 1;
    f32x4 ya = (f32x4)0.f;
    #pragma unroll 4
    for (int ks=0; ks<16; ++ks){
      bf16x8 bw = as_bf8(*(const u32x4*)(const void*)(WpF + (size_t)((((gs*2+nt2)*16 + ks)*64) + lane)*8));
      bf16x8 ah = *(const bf16x8*)(&hF[(ks*2 + mh)*256 + lane*4]);
      ya = __builtin_amdgcn_mfma_f32_16x16x32_bf16(ah, bw, ya, 0,0,0);
    }
    #pragma unroll
    for (int r=0;r<4;r++) yL[(mh*16 + q*4 + r)*33 + nt2*16 + c0] = ya[r];
    __syncthreads();
    if (wv == 3 && lane < 32) head_post(yL, bp, outp, gs, bg, lane, 256);
  }
}

extern "C" void kernel_launch(void* const* d_in, const int* in_sizes, int n_in,
                              void* d_out, int out_size, void* d_ws, size_t ws_size,
                              hipStream_t stream){
  (void)in_sizes; (void)n_in; (void)out_size; (void)ws_size;
  const float* backbone = (const float*)d_in[0];
  const float* z_vec    = (const float*)d_in[1];
  const float* sketch   = (const float*)d_in[2];
  const float* W_fc_hc  = (const float*)d_in[3];
  const float* b_fc_hc  = (const float*)d_in[4];
  const float* W_conv_h = (const float*)d_in[5];
  const float* b_conv_h = (const float*)d_in[6];
  const float* K_conv_f = (const float*)d_in[7];
  const float* b_conv_f = (const float*)d_in[8];
  const float* W_att    = (const float*)d_in[9];
  // d_in[10] = b_conv_att: additive constant to all scores -> softmax-invariant, skipped
  const float* W_ih     = (const float*)d_in[11];
  const float* W_hh     = (const float*)d_in[12];
  const float* b_ih     = (const float*)d_in[13];
  const float* b_hh     = (const float*)d_in[14];
  const float* W_fcp    = (const float*)d_in[15];
  const float* b_fcp    = (const float*)d_in[16];

  char* ws = (char*)d_ws;                        // total footprint: 22,953,984 B (~21.9 MB)
  u32*   slots    = (u32*)(ws + 0);              // 16,384
  u32*   h_pack   = (u32*)(ws + 16384);          // 262,144 (fragment-major per bg)
  u32*   att_pack = (u32*)(ws + 278528);         // 262,144 (fragment-major per bg)
  float* spart    = (float*)(ws + 540672);       // 2,097,152
  float* c_ws     = (float*)(ws + 2637824);      // 524,288
  u16*   x_em     = (u16*)(ws + 3162112);        // 8,388,608
  u16*   Wf       = (u16*)(ws + 11550720);       // 4,194,304
  u16*   Kf       = (u16*)(ws + 15745024);       // 2,359,296
  u32*   WcF      = (u32*)(ws + 18104320);       // 524,288
  u16*   WpF      = (u16*)(ws + 18628608);       // 131,072
  u16*   bb_bf    = (u16*)(ws + 18759680);       // 4,194,304

  (void)hipMemsetAsync(slots, 0, 16384, stream);
  k_prep_w  <<<8192, 256, 0, stream>>>(W_ih, W_hh, Wf);
  k_prep_kf <<<4608, 256, 0, stream>>>(K_conv_f, Kf);
  k_prep_wcf<<<512,  256, 0, stream>>>(W_conv_h, WcF);
  k_prep_wp <<<256,  256, 0, stream>>>(W_fcp, WpF);
  k_hc      <<<256,  256, 0, stream>>>(z_vec, W_fc_hc, b_fc_hc, h_pack, c_ws);
  k_conv    <<<256,  256, 0, stream>>>(backbone, Kf, b_conv_f, x_em, bb_bf);
  k_rnn     <<<256,  256, 0, stream>>>(bb_bf, sketch, b_conv_h, W_att, W_ih, b_ih, b_hh,
                                       x_em, Wf, WcF, WpF, b_fcp,
                                       h_pack, att_pack, spart, c_ws, slots, (float*)d_out);
}

// Round 2
// 7181.224 us; speedup vs baseline: 1.8393x; 1.1318x over previous
//
#include <hip/hip_runtime.h>
#include <hip/hip_bf16.h>

typedef unsigned short u16;
typedef unsigned int   u32;
typedef unsigned long long u64;

typedef __attribute__((ext_vector_type(8))) short bf16x8;  // 8 x bf16 (4 VGPR) MFMA A/B frag
typedef __attribute__((ext_vector_type(4))) float f32x4;   // MFMA C/D frag
typedef __attribute__((ext_vector_type(4))) u32   u32x4;

#define L2E 1.44269504088896340736f

__device__ __forceinline__ float bf2f(u16 u){ union{u32 i; float f;} v; v.i=((u32)u)<<16; return v.f; }
__device__ __forceinline__ u16  f2bf(float f){ union{float f; u32 i;} v; v.f=f; u32 u=v.i; return (u16)((u + 0x7fffu + ((u>>16)&1u))>>16); }
__device__ __forceinline__ u32  packbf(float a,float b){ return (u32)f2bf(a) | ((u32)f2bf(b)<<16); }
__device__ __forceinline__ float tanh_f(float x){
  float cx = fminf(fmaxf(x,-15.f),15.f);
  float e  = __builtin_amdgcn_exp2f(cx*(2.f*L2E));
  return (e-1.f)*__builtin_amdgcn_rcpf(e+1.f);
}
__device__ __forceinline__ float sig_f(float x){
  float cx = fminf(fmaxf(x,-30.f),30.f);
  float e  = __builtin_amdgcn_exp2f(-cx*L2E);
  return __builtin_amdgcn_rcpf(1.f+e);
}
// Cross-XCD coherent accesses: relaxed agent-scope atomics (bypass per-XCD caches; L3 = coherence point).
__device__ __forceinline__ u64   lda2(const u64* p){ return __hip_atomic_load((u64*)p, __ATOMIC_RELAXED, __HIP_MEMORY_SCOPE_AGENT); }
__device__ __forceinline__ void  sta(u32* p, u32 v){ __hip_atomic_store(p, v, __ATOMIC_RELAXED, __HIP_MEMORY_SCOPE_AGENT); }
__device__ __forceinline__ bf16x8 as_bf8(u32x4 w){ union{u32x4 u; bf16x8 b;} c; c.u=w; return c.b; }
// fragment-major address for an h/att element pair: batch r, u32-col c (h element pair 2c,2c+1)
__device__ __forceinline__ int frag_a(int r, int c){
  return ((c>>4)*2 + (r>>4))*256 + (((c>>2)&3))*64 + ((r&15))*4 + (c&3);
}

// ---------------- prep: W_ih/W_hh (f32) -> fragment-major bf16 Wf [gs][nt<4][ks<32][lane][8] ----------------
__global__ void k_prep_w(const float* __restrict__ W_ih, const float* __restrict__ W_hh, u16* __restrict__ Wf){
  int idx = blockIdx.x*256 + threadIdx.x;        // 2,097,152
  int j    = idx & 7;
  int lane = (idx >> 3) & 63;
  int ks   = (idx >> 9) & 31;
  int nt   = (idx >> 14) & 3;
  int gs   = idx >> 16;                          // < 32
  int grow = nt*512 + gs*16 + (lane & 15);       // global gate row (nt = gate i/f/g/o)
  int k    = ks*32 + ((lane >> 4) & 3)*8 + j;    // 0..1023: [att 512 | h 512]
  float v = (k < 512) ? W_ih[grow*517 + k] : W_hh[grow*512 + (k - 512)];
  Wf[idx] = f2bf(v);
}
// ---------------- prep: K_conv (f32) -> fragment-major bf16 Kf [tap][nt<16][ks<16][lane][8] ----------------
__global__ void k_prep_kf(const float* __restrict__ Kc, u16* __restrict__ Kf){
  int idx = blockIdx.x*256 + threadIdx.x;        // 1,179,648
  int j    = idx & 7;
  int lane = (idx >> 3) & 63;
  int ks   = (idx >> 9) & 15;
  int nt   = (idx >> 13) & 15;
  int tap  = idx >> 17;                          // < 9
  int oc = nt*16 + (lane & 15);
  int ic = ks*32 + ((lane >> 4) & 3)*8 + j;
  Kf[idx] = f2bf(Kc[(oc*512 + ic)*9 + tap]);
}
// ---------------- prep: W_conv_h (f32) -> FULL fragment-major bf16 WcF2 [nt<16][ks<16][lane][8] ----------------
// (Wf-style layout so every block can run the duplicated g_em GEMM straight out of L2.)
__global__ void k_prep_wcf2(const float* __restrict__ Wch, u16* __restrict__ WcF2){
  int idx = blockIdx.x*256 + threadIdx.x;        // 131,072
  int j = idx & 7, lane = (idx>>3) & 63, ks = (idx>>9) & 15, nt = idx >> 13;   // nt<16
  int e = nt*16 + (lane & 15);
  int k = ks*32 + ((lane >> 4) & 3)*8 + j;
  WcF2[idx] = f2bf(Wch[e*512 + k]);
}
// ---------------- prep: W_fc_params (f32) -> fragment-major bf16 WpF [ntile<8][ks<16][lane][8] ----------------
__global__ void k_prep_wp(const float* __restrict__ Wp, u16* __restrict__ WpF){
  int idx = blockIdx.x*256 + threadIdx.x;        // 65,536
  int j = idx & 7, lane = (idx>>3) & 63, ks = (idx>>9) & 15, ntile = idx >> 13;
  int n = ntile*16 + (lane & 15);
  int k = ks*32 + (lane >> 4)*8 + j;
  WpF[idx] = (n < 123) ? f2bf(Wp[n*512 + k]) : (u16)0;
}
// ---------------- init: hc = tanh(z @ W_fc_hc^T + b) -> h_pack (fragment-major bf16 pairs), c_ws (f32) ----------------
__global__ void k_hc(const float* __restrict__ z, const float* __restrict__ Wfc, const float* __restrict__ bfc,
                     u32* __restrict__ h_pack, float* __restrict__ c_ws){
  __shared__ float zl[128];
  int b = blockIdx.x, t = threadIdx.x;
  if (t < 128) zl[t] = z[b*128 + t];
  __syncthreads();
  float acc[4];
  #pragma unroll
  for (int i=0;i<4;i++){
    int n = 4*t + i;
    const float* row = Wfc + n*128;
    float a = 0.f;
    #pragma unroll 8
    for (int k2=0;k2<128;k2++) a += row[k2]*zl[k2];
    acc[i] = tanh_f(a + bfc[n]);
  }
  int bg = b >> 5, r = b & 31;
  if (t < 128){
    h_pack[bg*8192 + frag_a(r, 2*t)]   = packbf(acc[0], acc[1]);
    h_pack[bg*8192 + frag_a(r, 2*t+1)] = packbf(acc[2], acc[3]);
  } else {
    int base = 4*t - 512;
    #pragma unroll
    for (int i=0;i<4;i++) c_ws[b*512 + base + i] = acc[i];
  }
}
// ---------------- conv 3x3 SAME (f32 in, bf16 out) + bf16 backbone copy ----------------
__device__ __forceinline__ int xt_addr(int p, int chunk){ return p*512 + ((chunk ^ (p & 7))<<3); } // XOR-swizzled LDS
__global__ __launch_bounds__(256) void k_conv(const float* __restrict__ bb, const u16* __restrict__ Kf,
                       const float* __restrict__ bcf, u16* __restrict__ x_em, u16* __restrict__ bb_bf){
  __shared__ u16 xt[64*512];  // exactly 64KB, swizzled [p][ic]
  int b = blockIdx.x, t = threadIdx.x;
  const float* src = bb + (size_t)b*512*64;
  u16* dstc = bb_bf + (size_t)b*512*64;
  for (int i=0;i<128;i++){
    int idx = i*256 + t;
    int ic = idx >> 6, p = idx & 63;
    u16 v = f2bf(src[idx]);
    xt[xt_addr(p, ic>>3) + (ic&7)] = v;
    dstc[idx] = v;                         // bf16 copy, same [b][c][p] layout
  }
  __syncthreads();
  int wv = t >> 6, l = t & 63, c0 = l & 15, q = l >> 4;
  f32x4 acc[4][4];
  #pragma unroll
  for (int a=0;a<4;a++)
    #pragma unroll
    for (int bq=0;bq<4;bq++) acc[a][bq] = (f32x4)0.f;
  for (int tap=0; tap<9; ++tap){
    int ty = tap/3 - 1, tx = tap%3 - 1;
    for (int ks=0; ks<16; ++ks){
      bf16x8 afr[4];
      #pragma unroll
      for (int mt=0; mt<4; ++mt){
        int p = mt*16 + c0;
        int py = (p >> 3) + ty, px = (p & 7) + tx;
        if ((unsigned)py < 8u && (unsigned)px < 8u){
          afr[mt] = *(const bf16x8*)(&xt[xt_addr(py*8+px, ks*4 + q)]);
        } else {
          afr[mt] = (bf16x8)0;
        }
      }
      #pragma unroll
      for (int ni=0; ni<4; ++ni){
        int nt = wv*4 + ni;
        bf16x8 bfr = as_bf8(*(const u32x4*)(const void*)(Kf + (size_t)((((tap*16 + nt)*16 + ks)*64) + l)*8));
        #pragma unroll
        for (int mt=0; mt<4; ++mt)
          acc[mt][ni] = __builtin_amdgcn_mfma_f32_16x16x32_bf16(afr[mt], bfr, acc[mt][ni], 0,0,0);
      }
    }
  }
  #pragma unroll
  for (int ni=0; ni<4; ++ni){
    int e = (wv*4+ni)*16 + c0;
    float bias = bcf[e];
    #pragma unroll
    for (int mt=0; mt<4; ++mt)
      #pragma unroll
      for (int r=0;r<4;r++){
        int p = mt*16 + q*4 + r;
        x_em[(size_t)(b*256 + e)*64 + p] = f2bf(acc[mt][ni][r] + bias);
      }
  }
}

// ---------------- split barrier: arrive = counter atomicAdd at L3 (immediate visibility at coherence
// point, single hot line per bg); wait = 1-thread poll + block release. Data ordering: __syncthreads'
// vmcnt(0) drain acks all agent-scope write-through stores at L3 before the arrive atomic issues. ----------------
__device__ __forceinline__ void bar_arrive(u32* cnt, int bg, int t){
  __syncthreads();   // all waves' agent-scope data stores acked at coherence point
  if (t == 0) (void)__hip_atomic_fetch_add(&cnt[bg*32], 1u, __ATOMIC_RELAXED, __HIP_MEMORY_SCOPE_AGENT);
}
__device__ __forceinline__ void bar_wait(u32* cnt, int bg, int t, u32 target){
  if (t == 0){
    while (__hip_atomic_load(&cnt[bg*32], __ATOMIC_RELAXED, __HIP_MEMORY_SCOPE_AGENT) < target)
      __builtin_amdgcn_s_sleep(1);
  }
  __atomic_signal_fence(__ATOMIC_ACQUIRE);   // compiler barrier only: data loads stay after the spin
  __syncthreads();
}

// ---------------- head postprocess for one batch row (32-col superblock gs); nontemporal f32 out ----------------
__device__ __forceinline__ void head_post(const float* yL, const float* __restrict__ bp,
                                          float* __restrict__ out, int gs, int bg, int bL2, int step){
  const int CH = 1315840;          // 65792*20
  const int PEN = 7895040;         // 6*CH
  int rr = (bg*32 + bL2)*257 + step;
  float m = -1e30f, rs = 0.f;
  if (gs == 0){
    float su = 0.f;
    #pragma unroll 1
    for (int c=3;c<23;c++){ float v = yL[bL2*33 + c] + bp[c]; m = fmaxf(m, v); }
    #pragma unroll 1
    for (int c=3;c<23;c++){ float v = yL[bL2*33 + c] + bp[c]; su += __builtin_amdgcn_exp2f((v-m)*L2E); }
    rs = __builtin_amdgcn_rcpf(su);
  }
  #pragma unroll 1
  for (int c2=0;c2<32;c2++){
    int col = gs*32 + c2;
    if (col >= 123) break;
    float v = yL[bL2*33 + c2] + bp[col];
    float tv; int oidx;
    if (col < 3){ tv = v; oidx = PEN + rr*3 + col; }
    else {
      int j = col - 3, ch = j/20, jj = j - ch*20;
      if (ch == 0)      tv = __builtin_amdgcn_exp2f((v-m)*L2E)*rs;
      else if (ch <= 2) tv = v;
      else if (ch <= 4) tv = __builtin_amdgcn_exp2f(v*L2E);
      else              tv = tanh_f(v);
      oidx = ch*CH + rr*20 + jj;
    }
    __builtin_nontemporal_store(tv, &out[oidx]);
  }
}

// ---------------- persistent RNN scan + fused head: 8 bg-groups x 32 gs-blocks, 2 barriers/step ----------------
__global__ __launch_bounds__(256) void k_rnn(
    const u16* __restrict__ bb_bf, const float* __restrict__ sketch,
    const float* __restrict__ b_ch, const float* __restrict__ Watt,
    const float* __restrict__ W_ih, const float* __restrict__ b_ih, const float* __restrict__ b_hh,
    const u16* __restrict__ x_em, const u16* __restrict__ Wf, const u16* __restrict__ WcF2,
    const u16* __restrict__ WpF, const float* __restrict__ bp,
    u32* __restrict__ h_pack, u32* __restrict__ att_pack,
    const float* __restrict__ c_ws, u32* __restrict__ cnt, float* __restrict__ outp)
{
  __shared__ u32 hF[8192];        // 32KB: h fragments; re-used as att fragments during B-att phase
  __shared__ u32 xaH[4096];       // 16KB: score staging (8KB) / gates buffer (8.4KB), phase-aliased
  __shared__ float gemA[256];     // g_em row for own batch (bias folded)
  __shared__ float wattA[256];
  __shared__ float bchA[256];
  __shared__ float alphaL[64];
  __shared__ float ptL[32*8];
  __shared__ float w5L[64*8];
  __shared__ float biasL[64];
  __shared__ float yL[32*33];     // head y staging (4.2KB)
  float* gbufL = (float*)xaH;
  float* stgL  = (float*)xaH;

  int t = threadIdx.x;
  int bg = blockIdx.x >> 5, gs = blockIdx.x & 31;
  int lane = t & 63, wv = t >> 6;
  int c0 = lane & 15, q = lane >> 4;

  // one-time staging
  wattA[t] = Watt[t];
  bchA[t]  = b_ch[t];
  if (t < 64){
    int grow = (t >> 4)*512 + gs*16 + (t & 15);
    biasL[t] = b_ih[grow] + b_hh[grow];
    #pragma unroll
    for (int d=0; d<5; ++d) w5L[t*8+d] = W_ih[grow*517 + 512 + d];
  }
  int bL = t & 31, hp = t >> 5;              // LSTM role
  int gb_l = bg*32 + bL;
  float c0r = c_ws[gb_l*512 + gs*16 + 2*hp];
  float c1r = c_ws[gb_l*512 + gs*16 + 2*hp + 1];
  int ba = bg*32 + gs;                       // own batch
  int mh_g = gs >> 4;                        // m-half holding our batch row
  int rq = (gs & 15) >> 2, rj = gs & 3;      // quad / reg of our row in the C-frag
  const u16* wb  = Wf   + (size_t)(((gs*4 + wv)*32)*64 + lane)*8;
  const u16* wcb = WcF2 + (size_t)((wv*4)*16*64 + lane)*8;   // g_em weight base for ni=0
  const u64* hsrc = (const u64*)(h_pack + (size_t)bg*8192);
  u64* hdst = (u64*)hF;
  const u64* asrc = (const u64*)(att_pack + (size_t)bg*8192);
  int hpub_a = frag_a(bL, gs*8 + hp);        // h publish slot (fragment-major)
  int apub_a = ((gs>>4)<<12) + ((t>>4)<<8) + (((t>>2)&3)<<6) + ((gs&15)<<2) + (t&3);  // att publish slot
  u32 seq = 0;
  __syncthreads();

  #pragma clang loop unroll(disable)
  for (int ts=0; ts<257; ++ts){
    // ======== stage h (fragment-major memcpy: coalesced ull atomics -> dense ds_write_b64) ========
    #pragma unroll
    for (int k=0;k<16;k++){
      int idx = k*256 + t;
      hdst[idx] = lda2(&hsrc[idx]);
    }
    __syncthreads();
    // ======== A-gem: duplicated g_em GEMM (32x256x512), keep only own row ba ========
    {
      f32x4 ge0 = (f32x4)0.f, ge1 = (f32x4)0.f, ge2 = (f32x4)0.f, ge3 = (f32x4)0.f;
      #pragma unroll 4
      for (int ks=0; ks<16; ++ks){
        bf16x8 ahk = *(const bf16x8*)(&hF[(ks*2 + mh_g)*256 + lane*4]);
        bf16x8 b0 = as_bf8(*(const u32x4*)(const void*)(wcb + (size_t)(0*16 + ks)*512));
        bf16x8 b1 = as_bf8(*(const u32x4*)(const void*)(wcb + (size_t)(1*16 + ks)*512));
        bf16x8 b2 = as_bf8(*(const u32x4*)(const void*)(wcb + (size_t)(2*16 + ks)*512));
        bf16x8 b3 = as_bf8(*(const u32x4*)(const void*)(wcb + (size_t)(3*16 + ks)*512));
        ge0 = __builtin_amdgcn_mfma_f32_16x16x32_bf16(ahk, b0, ge0, 0,0,0);
        ge1 = __builtin_amdgcn_mfma_f32_16x16x32_bf16(ahk, b1, ge1, 0,0,0);
        ge2 = __builtin_amdgcn_mfma_f32_16x16x32_bf16(ahk, b2, ge2, 0,0,0);
        ge3 = __builtin_amdgcn_mfma_f32_16x16x32_bf16(ahk, b3, ge3, 0,0,0);
      }
      if (q == rq){
        gemA[(wv*4+0)*16 + c0] = ge0[rj] + bchA[(wv*4+0)*16 + c0];
        gemA[(wv*4+1)*16 + c0] = ge1[rj] + bchA[(wv*4+1)*16 + c0];
        gemA[(wv*4+2)*16 + c0] = ge2[rj] + bchA[(wv*4+2)*16 + c0];
        gemA[(wv*4+3)*16 + c0] = ge3[rj] + bchA[(wv*4+3)*16 + c0];
      }
    }
    __syncthreads();
    // ======== A-score: full 256-e scores for OWN batch; thread=(e-group eg, p-octet ps) ========
    {
      int eg = t >> 3, ps = t & 7;
      float sp[8];
      #pragma unroll
      for (int j=0;j<8;j++) sp[j] = 0.f;
      const u16* xb = x_em + (size_t)(ba*256 + eg*8)*64 + ps*8;
      #pragma unroll
      for (int e2=0; e2<8; ++e2){
        float gev = gemA[eg*8 + e2];
        float wev = wattA[eg*8 + e2];
        bf16x8 xv = *(const bf16x8*)(xb + (size_t)e2*64);
        #pragma unroll
        for (int j=0;j<8;j++)
          sp[j] += tanh_f(bf2f((u16)xv[j]) + gev) * wev;
      }
      #pragma unroll
      for (int j=0;j<8;j++) stgL[eg*64 + ps*8 + j] = sp[j];
    }
    __syncthreads();
    if (t < 64){
      float s = 0.f;
      #pragma unroll
      for (int g2=0; g2<32; ++g2) s += stgL[g2*64 + t];
      float m = s;
      #pragma unroll
      for (int d=1; d<64; d<<=1) m = fmaxf(m, __shfl_xor(m, d, 64));
      float ex = __builtin_amdgcn_exp2f((s - m) * L2E);
      float su = ex;
      #pragma unroll
      for (int d=1; d<64; d<<=1) su += __shfl_xor(su, d, 64);
      alphaL[t] = ex * __builtin_amdgcn_rcpf(su);
    }
    __syncthreads();
    {  // att[c] = sum_p alpha[p]*backbone[ba][c][p]; thread handles c = 2t, 2t+1
      const u16* base = bb_bf + (size_t)(ba*512 + 2*t)*64;
      float a0 = 0.f, a1 = 0.f;
      #pragma unroll
      for (int p8=0; p8<8; ++p8){
        bf16x8 v0 = *(const bf16x8*)(base + p8*8);
        bf16x8 v1 = *(const bf16x8*)(base + 64 + p8*8);
        #pragma unroll
        for (int j=0;j<8;j++){
          float al = alphaL[p8*8+j];
          a0 += al * bf2f((u16)v0[j]);
          a1 += al * bf2f((u16)v1[j]);
        }
      }
      sta(&att_pack[(size_t)bg*8192 + apub_a], packbf(a0, a1));
    }
    seq++; bar_arrive(cnt, bg, t);
    // ======== barrier-1 shadow: head C for step ts-1 (hF still = h_{ts-1}), pt staging, h-half gates ========
    if (gs < 4 && ts > 0){
      int mh = wv & 1, nt2 = wv >> 1;
      f32x4 ya = (f32x4)0.f;
      #pragma unroll 4
      for (int ks=0; ks<16; ++ks){
        bf16x8 bw = as_bf8(*(const u32x4*)(const void*)(WpF + (size_t)((((gs*2+nt2)*16 + ks)*64) + lane)*8));
        bf16x8 ah = *(const bf16x8*)(&hF[(ks*2 + mh)*256 + lane*4]);
        ya = __builtin_amdgcn_mfma_f32_16x16x32_bf16(ah, bw, ya, 0,0,0);
      }
      #pragma unroll
      for (int r=0;r<4;r++) yL[(mh*16 + q*4 + r)*33 + nt2*16 + c0] = ya[r];
      __syncthreads();
      if (wv == 3 && lane < 32) head_post(yL, bp, outp, gs, bg, lane, ts-1);
    }
    if (t < 32){
      float p0,p1,p2,p3,p4;
      if (ts == 0){ p0=0.f;p1=0.f;p2=1.f;p3=0.f;p4=0.f; }
      else {
        const float* sp = sketch + ((size_t)(ts-1)*256 + (bg*32 + t))*5;
        p0=sp[0]; p1=sp[1]; p2=sp[2]; p3=sp[3]; p4=sp[4];
      }
      ptL[t*8+0]=p0; ptL[t*8+1]=p1; ptL[t*8+2]=p2; ptL[t*8+3]=p3; ptL[t*8+4]=p4;
    }
    // h-half of gates (local hF only — no dependency on the att barrier)
    f32x4 acc0 = (f32x4)0.f, acc1 = (f32x4)0.f;
    #pragma unroll 4
    for (int ks2=0; ks2<16; ++ks2){
      bf16x8 bfr = as_bf8(*(const u32x4*)(const void*)(wb + (size_t)(16+ks2)*512));
      bf16x8 a0 = *(const bf16x8*)(&hF[(ks2*2)*256 + lane*4]);
      bf16x8 a1 = *(const bf16x8*)(&hF[(ks2*2+1)*256 + lane*4]);
      acc0 = __builtin_amdgcn_mfma_f32_16x16x32_bf16(a0, bfr, acc0, 0,0,0);
      acc1 = __builtin_amdgcn_mfma_f32_16x16x32_bf16(a1, bfr, acc1, 0,0,0);
    }
    bar_wait(cnt, bg, t, 32u*seq);
    // ======== B: stage FULL att (32KB, one L3 round) into hF region; att-half gates; LSTM; publish h ========
    #pragma unroll
    for (int k=0;k<16;k++){
      int idx = k*256 + t;
      hdst[idx] = lda2(&asrc[idx]);
    }
    __syncthreads();
    #pragma unroll 4
    for (int kc=0; kc<16; ++kc){
      bf16x8 bfr = as_bf8(*(const u32x4*)(const void*)(wb + (size_t)kc*512));
      bf16x8 af0 = *(const bf16x8*)(&hF[kc*256 + lane*4]);
      bf16x8 af1 = *(const bf16x8*)(&hF[4096 + kc*256 + lane*4]);
      acc0 = __builtin_amdgcn_mfma_f32_16x16x32_bf16(af0, bfr, acc0, 0,0,0);
      acc1 = __builtin_amdgcn_mfma_f32_16x16x32_bf16(af1, bfr, acc1, 0,0,0);
    }
    {
      int n = wv*16 + c0;
      #pragma unroll
      for (int r=0;r<4;r++){
        gbufL[n*33 + (q*4 + r)]      = acc0[r];
        gbufL[n*33 + (16 + q*4 + r)] = acc1[r];
      }
    }
    __syncthreads();
    {
      float p0v = ptL[bL*8+0], p1v = ptL[bL*8+1], p2v = ptL[bL*8+2], p3v = ptL[bL*8+3], p4v = ptL[bL*8+4];
      auto gval = [&](int n)->float {
        return gbufL[n*33 + bL] + biasL[n]
             + p0v*w5L[n*8+0] + p1v*w5L[n*8+1] + p2v*w5L[n*8+2] + p3v*w5L[n*8+3] + p4v*w5L[n*8+4];
      };
      float hv0 = 0.f, hv1 = 0.f;
      #pragma unroll
      for (int k2=0;k2<2;k2++){
        int hh = 2*hp + k2;
        float gi = gval(hh), gf = gval(16+hh), gg = gval(32+hh), go = gval(48+hh);
        float cp = k2 ? c1r : c0r;
        float cn = sig_f(gf)*cp + sig_f(gi)*tanh_f(gg);
        float hv = sig_f(go)*tanh_f(cn);
        if (k2){ c1r = cn; hv1 = hv; } else { c0r = cn; hv0 = hv; }
      }
      sta(&h_pack[(size_t)bg*8192 + hpub_a], packbf(hv0, hv1));
    }
    seq++; bar_arrive(cnt, bg, t);
    bar_wait(cnt, bg, t, 32u*seq);
  }
  // ======== epilogue: head for step 256 (h_256 now in h_pack) ========
  if (gs < 4){
    #pragma unroll
    for (int k=0;k<16;k++){
      int idx = k*256 + t;
      hdst[idx] = lda2(&hsrc[idx]);
    }
    __syncthreads();
    int mh = wv & 1, nt2 = wv >> 1;
    f32x4 ya = (f32x4)0.f;
    #pragma unroll 4
    for (int ks=0; ks<16; ++ks){
      bf16x8 bw = as_bf8(*(const u32x4*)(const void*)(WpF + (size_t)((((gs*2+nt2)*16 + ks)*64) + lane)*8));
      bf16x8 ah = *(const bf16x8*)(&hF[(ks*2 + mh)*256 + lane*4]);
      ya = __builtin_amdgcn_mfma_f32_16x16x32_bf16(ah, bw, ya, 0,0,0);
    }
    #pragma unroll
    for (int r=0;r<4;r++) yL[(mh*16 + q*4 + r)*33 + nt2*16 + c0] = ya[r];
    __syncthreads();
    if (wv == 3 && lane < 32) head_post(yL, bp, outp, gs, bg, lane, 256);
  }
}

extern "C" void kernel_launch(void* const* d_in, const int* in_sizes, int n_in,
                              void* d_out, int out_size, void* d_ws, size_t ws_size,
                              hipStream_t stream){
  (void)in_sizes; (void)n_in; (void)out_size; (void)ws_size;
  const float* backbone = (const float*)d_in[0];
  const float* z_vec    = (const float*)d_in[1];
  const float* sketch   = (const float*)d_in[2];
  const float* W_fc_hc  = (const float*)d_in[3];
  const float* b_fc_hc  = (const float*)d_in[4];
  const float* W_conv_h = (const float*)d_in[5];
  const float* b_conv_h = (const float*)d_in[6];
  const float* K_conv_f = (const float*)d_in[7];
  const float* b_conv_f = (const float*)d_in[8];
  const float* W_att    = (const float*)d_in[9];
  // d_in[10] = b_conv_att: additive constant to all scores -> softmax-invariant, skipped
  const float* W_ih     = (const float*)d_in[11];
  const float* W_hh     = (const float*)d_in[12];
  const float* b_ih     = (const float*)d_in[13];
  const float* b_hh     = (const float*)d_in[14];
  const float* W_fcp    = (const float*)d_in[15];
  const float* b_fcp    = (const float*)d_in[16];

  char* ws = (char*)d_ws;
  u32*   cnt      = (u32*)(ws + 0);              // 16,384 (8 counters, 128B apart)
  u32*   h_pack   = (u32*)(ws + 16384);          // 262,144 (fragment-major per bg)
  u32*   att_pack = (u32*)(ws + 278528);         // 262,144 (fragment-major per bg)
  float* c_ws     = (float*)(ws + 2637824);      // 524,288
  u16*   x_em     = (u16*)(ws + 3162112);        // 8,388,608
  u16*   Wf       = (u16*)(ws + 11550720);       // 4,194,304
  u16*   Kf       = (u16*)(ws + 15745024);       // 2,359,296
  u16*   WcF2     = (u16*)(ws + 18104320);       // 262,144
  u16*   WpF      = (u16*)(ws + 18628608);       // 131,072
  u16*   bb_bf    = (u16*)(ws + 18759680);       // 4,194,304

  (void)hipMemsetAsync(cnt, 0, 16384, stream);
  k_prep_w  <<<8192, 256, 0, stream>>>(W_ih, W_hh, Wf);
  k_prep_kf <<<4608, 256, 0, stream>>>(K_conv_f, Kf);
  k_prep_wcf2<<<512, 256, 0, stream>>>(W_conv_h, WcF2);
  k_prep_wp <<<256,  256, 0, stream>>>(W_fcp, WpF);
  k_hc      <<<256,  256, 0, stream>>>(z_vec, W_fc_hc, b_fc_hc, h_pack, c_ws);
  k_conv    <<<256,  256, 0, stream>>>(backbone, Kf, b_conv_f, x_em, bb_bf);
  k_rnn     <<<256,  256, 0, stream>>>(bb_bf, sketch, b_conv_h, W_att, W_ih, b_ih, b_hh,
                                       x_em, Wf, WcF2, WpF, b_fcp,
                                       h_pack, att_pack, c_ws, cnt, (float*)d_out);
}

// Round 5
// 6052.098 us; speedup vs baseline: 2.1825x; 1.1866x over previous
//
#include <hip/hip_runtime.h>
#include <hip/hip_bf16.h>

typedef unsigned short u16;
typedef unsigned int   u32;
typedef unsigned long long u64;

typedef __attribute__((ext_vector_type(8))) short bf16x8;  // 8 x bf16 (4 VGPR) MFMA A/B frag
typedef __attribute__((ext_vector_type(4))) float f32x4;   // MFMA C/D frag
typedef __attribute__((ext_vector_type(4))) u32   u32x4;

#define L2E 1.44269504088896340736f

__device__ __forceinline__ float bf2f(u16 u){ union{u32 i; float f;} v; v.i=((u32)u)<<16; return v.f; }
__device__ __forceinline__ u16  f2bf(float f){ union{float f; u32 i;} v; v.f=f; u32 u=v.i; return (u16)((u + 0x7fffu + ((u>>16)&1u))>>16); }
__device__ __forceinline__ u32  packbf(float a,float b){ return (u32)f2bf(a) | ((u32)f2bf(b)<<16); }
__device__ __forceinline__ float tanh_f(float x){
  float cx = fminf(fmaxf(x,-15.f),15.f);
  float e  = __builtin_amdgcn_exp2f(cx*(2.f*L2E));
  return (e-1.f)*__builtin_amdgcn_rcpf(e+1.f);
}
__device__ __forceinline__ float sig_f(float x){
  float cx = fminf(fmaxf(x,-30.f),30.f);
  float e  = __builtin_amdgcn_exp2f(-cx*L2E);
  return __builtin_amdgcn_rcpf(1.f+e);
}
// Cross-XCD coherent accesses: relaxed agent-scope atomics (bypass per-XCD caches; L3 = coherence point).
__device__ __forceinline__ u64   lda2(const u64* p){ return __hip_atomic_load((u64*)p, __ATOMIC_RELAXED, __HIP_MEMORY_SCOPE_AGENT); }
__device__ __forceinline__ void  sta(u32* p, u32 v){ __hip_atomic_store(p, v, __ATOMIC_RELAXED, __HIP_MEMORY_SCOPE_AGENT); }
__device__ __forceinline__ bf16x8 as_bf8(u32x4 w){ union{u32x4 u; bf16x8 b;} c; c.u=w; return c.b; }
// fragment-major address for an h/att element pair: batch r, u32-col c (h element pair 2c,2c+1)
__device__ __forceinline__ int frag_a(int r, int c){
  return ((c>>4)*2 + (r>>4))*256 + (((c>>2)&3))*64 + ((r&15))*4 + (c&3);
}

// ---- batched 32KB L3->LDS stage: 16 independent agent-scope u64 loads into registers (all in flight,
// no ds_write data-dep between them), then 16 ds_write_b64. One latency epoch instead of 16 serial
// load->waitcnt->write round trips. ----
__device__ __forceinline__ void stage32i(u32* lds, const u32* gsrc, int t){
  const u64* g = (const u64*)gsrc;
  u64* d = (u64*)lds;
  u64 r[16];
  #pragma unroll
  for (int k=0;k<16;k++) r[k] = lda2(&g[k*256 + t]);
  #pragma unroll
  for (int k=0;k<16;k++) d[k*256 + t] = r[k];
}

// ---------------- prep: W_ih/W_hh (f32) -> fragment-major bf16 Wf [gs][nt<4][ks<32][lane][8] ----------------
__global__ void k_prep_w(const float* __restrict__ W_ih, const float* __restrict__ W_hh, u16* __restrict__ Wf){
  int idx = blockIdx.x*256 + threadIdx.x;        // 2,097,152
  int j    = idx & 7;
  int lane = (idx >> 3) & 63;
  int ks   = (idx >> 9) & 31;
  int nt   = (idx >> 14) & 3;
  int gs   = idx >> 16;                          // < 32
  int grow = nt*512 + gs*16 + (lane & 15);       // global gate row (nt = gate i/f/g/o)
  int k    = ks*32 + ((lane >> 4) & 3)*8 + j;    // 0..1023: [att 512 | h 512]
  float v = (k < 512) ? W_ih[grow*517 + k] : W_hh[grow*512 + (k - 512)];
  Wf[idx] = f2bf(v);
}
// ---------------- prep: K_conv (f32) -> fragment-major bf16 Kf [tap][nt<16][ks<16][lane][8] ----------------
__global__ void k_prep_kf(const float* __restrict__ Kc, u16* __restrict__ Kf){
  int idx = blockIdx.x*256 + threadIdx.x;        // 1,179,648
  int j    = idx & 7;
  int lane = (idx >> 3) & 63;
  int ks   = (idx >> 9) & 15;
  int nt   = (idx >> 13) & 15;
  int tap  = idx >> 17;                          // < 9
  int oc = nt*16 + (lane & 15);
  int ic = ks*32 + ((lane >> 4) & 3)*8 + j;
  Kf[idx] = f2bf(Kc[(oc*512 + ic)*9 + tap]);
}
// ---------------- prep: W_conv_h (f32) -> FULL fragment-major bf16 WcF2 [nt<16][ks<16][lane][8] ----------------
__global__ void k_prep_wcf2(const float* __restrict__ Wch, u16* __restrict__ WcF2){
  int idx = blockIdx.x*256 + threadIdx.x;        // 131,072
  int j = idx & 7, lane = (idx>>3) & 63, ks = (idx>>9) & 15, nt = idx >> 13;   // nt<16
  int e = nt*16 + (lane & 15);
  int k = ks*32 + ((lane >> 4) & 3)*8 + j;
  WcF2[idx] = f2bf(Wch[e*512 + k]);
}
// ---------------- prep: W_fc_params (f32) -> fragment-major bf16 WpF [ntile<8][ks<16][lane][8] ----------------
__global__ void k_prep_wp(const float* __restrict__ Wp, u16* __restrict__ WpF){
  int idx = blockIdx.x*256 + threadIdx.x;        // 65,536
  int j = idx & 7, lane = (idx>>3) & 63, ks = (idx>>9) & 15, ntile = idx >> 13;
  int n = ntile*16 + (lane & 15);
  int k = ks*32 + (lane >> 4)*8 + j;
  WpF[idx] = (n < 123) ? f2bf(Wp[n*512 + k]) : (u16)0;
}
// ---------------- init: hc = tanh(z @ W_fc_hc^T + b) -> h_pack (fragment-major bf16 pairs), c_ws (f32) ----------------
__global__ void k_hc(const float* __restrict__ z, const float* __restrict__ Wfc, const float* __restrict__ bfc,
                     u32* __restrict__ h_pack, float* __restrict__ c_ws){
  __shared__ float zl[128];
  int b = blockIdx.x, t = threadIdx.x;
  if (t < 128) zl[t] = z[b*128 + t];
  __syncthreads();
  float acc[4];
  #pragma unroll
  for (int i=0;i<4;i++){
    int n = 4*t + i;
    const float* row = Wfc + n*128;
    float a = 0.f;
    #pragma unroll 8
    for (int k2=0;k2<128;k2++) a += row[k2]*zl[k2];
    acc[i] = tanh_f(a + bfc[n]);
  }
  int bg = b >> 5, r = b & 31;
  if (t < 128){
    h_pack[bg*8192 + frag_a(r, 2*t)]   = packbf(acc[0], acc[1]);
    h_pack[bg*8192 + frag_a(r, 2*t+1)] = packbf(acc[2], acc[3]);
  } else {
    int base = 4*t - 512;
    #pragma unroll
    for (int i=0;i<4;i++) c_ws[b*512 + base + i] = acc[i];
  }
}
// ---------------- conv 3x3 SAME (f32 in, bf16 out) + bf16 backbone copy ----------------
__device__ __forceinline__ int xt_addr(int p, int chunk){ return p*512 + ((chunk ^ (p & 7))<<3); } // XOR-swizzled LDS
__global__ __launch_bounds__(256) void k_conv(const float* __restrict__ bb, const u16* __restrict__ Kf,
                       const float* __restrict__ bcf, u16* __restrict__ x_em, u16* __restrict__ bb_bf){
  __shared__ u16 xt[64*512];  // exactly 64KB, swizzled [p][ic]
  int b = blockIdx.x, t = threadIdx.x;
  const float* src = bb + (size_t)b*512*64;
  u16* dstc = bb_bf + (size_t)b*512*64;
  for (int i=0;i<128;i++){
    int idx = i*256 + t;
    int ic = idx >> 6, p = idx & 63;
    u16 v = f2bf(src[idx]);
    xt[xt_addr(p, ic>>3) + (ic&7)] = v;
    dstc[idx] = v;                         // bf16 copy, same [b][c][p] layout
  }
  __syncthreads();
  int wv = t >> 6, l = t & 63, c0 = l & 15, q = l >> 4;
  f32x4 acc[4][4];
  #pragma unroll
  for (int a=0;a<4;a++)
    #pragma unroll
    for (int bq=0;bq<4;bq++) acc[a][bq] = (f32x4)0.f;
  for (int tap=0; tap<9; ++tap){
    int ty = tap/3 - 1, tx = tap%3 - 1;
    for (int ks=0; ks<16; ++ks){
      bf16x8 afr[4];
      #pragma unroll
      for (int mt=0; mt<4; ++mt){
        int p = mt*16 + c0;
        int py = (p >> 3) + ty, px = (p & 7) + tx;
        if ((unsigned)py < 8u && (unsigned)px < 8u){
          afr[mt] = *(const bf16x8*)(&xt[xt_addr(py*8+px, ks*4 + q)]);
        } else {
          afr[mt] = (bf16x8)0;
        }
      }
      #pragma unroll
      for (int ni=0; ni<4; ++ni){
        int nt = wv*4 + ni;
        bf16x8 bfr = as_bf8(*(const u32x4*)(const void*)(Kf + (size_t)((((tap*16 + nt)*16 + ks)*64) + l)*8));
        #pragma unroll
        for (int mt=0; mt<4; ++mt)
          acc[mt][ni] = __builtin_amdgcn_mfma_f32_16x16x32_bf16(afr[mt], bfr, acc[mt][ni], 0,0,0);
      }
    }
  }
  #pragma unroll
  for (int ni=0; ni<4; ++ni){
    int e = (wv*4+ni)*16 + c0;
    float bias = bcf[e];
    #pragma unroll
    for (int mt=0; mt<4; ++mt)
      #pragma unroll
      for (int r=0;r<4;r++){
        int p = mt*16 + q*4 + r;
        x_em[(size_t)(b*256 + e)*64 + p] = f2bf(acc[mt][ni][r] + bias);
      }
  }
}

// ---------------- split barrier (proven single-line form): arrive = counter atomicAdd at L3;
// wait = 1-thread poll + block release. Data ordering: __syncthreads' vmcnt(0) drain acks all
// agent-scope write-through stores at the coherence point before the counter bump issues. ----------------
__device__ __forceinline__ void bar_arrive(u32* cnt, int bg, int t){
  __syncthreads();   // all waves' agent-scope data stores acked at coherence point
  if (t == 0) (void)__hip_atomic_fetch_add(&cnt[bg*32], 1u, __ATOMIC_RELAXED, __HIP_MEMORY_SCOPE_AGENT);
}
__device__ __forceinline__ void bar_wait(u32* cnt, int bg, int t, u32 target){
  if (t == 0){
    while (__hip_atomic_load(&cnt[bg*32], __ATOMIC_RELAXED, __HIP_MEMORY_SCOPE_AGENT) < target)
      __builtin_amdgcn_s_sleep(1);
  }
  __atomic_signal_fence(__ATOMIC_ACQUIRE);   // compiler barrier only: data loads stay after the spin
  __syncthreads();
}

// ---------------- head postprocess for one batch row (32-col superblock gs); nontemporal f32 out ----------------
__device__ __forceinline__ void head_post(const float* yL, const float* __restrict__ bp,
                                          float* __restrict__ out, int gs, int bg, int bL2, int step){
  const int CH = 1315840;          // 65792*20
  const int PEN = 7895040;         // 6*CH
  int rr = (bg*32 + bL2)*257 + step;
  float m = -1e30f, rs = 0.f;
  if (gs == 0){
    float su = 0.f;
    #pragma unroll 1
    for (int c=3;c<23;c++){ float v = yL[bL2*33 + c] + bp[c]; m = fmaxf(m, v); }
    #pragma unroll 1
    for (int c=3;c<23;c++){ float v = yL[bL2*33 + c] + bp[c]; su += __builtin_amdgcn_exp2f((v-m)*L2E); }
    rs = __builtin_amdgcn_rcpf(su);
  }
  #pragma unroll 1
  for (int c2=0;c2<32;c2++){
    int col = gs*32 + c2;
    if (col >= 123) break;
    float v = yL[bL2*33 + c2] + bp[col];
    float tv; int oidx;
    if (col < 3){ tv = v; oidx = PEN + rr*3 + col; }
    else {
      int j = col - 3, ch = j/20, jj = j - ch*20;
      if (ch == 0)      tv = __builtin_amdgcn_exp2f((v-m)*L2E)*rs;
      else if (ch <= 2) tv = v;
      else if (ch <= 4) tv = __builtin_amdgcn_exp2f(v*L2E);
      else              tv = tanh_f(v);
      oidx = ch*CH + rr*20 + jj;
    }
    __builtin_nontemporal_store(tv, &out[oidx]);
  }
}

// ---------------- persistent RNN scan + fused head: 8 bg-groups x 32 gs-blocks, 2 barriers/step ----------------
__global__ __launch_bounds__(256) void k_rnn(
    const u16* __restrict__ bb_bf, const float* __restrict__ sketch,
    const float* __restrict__ b_ch, const float* __restrict__ Watt,
    const float* __restrict__ W_ih, const float* __restrict__ b_ih, const float* __restrict__ b_hh,
    const u16* __restrict__ x_em, const u16* __restrict__ Wf, const u16* __restrict__ WcF2,
    const u16* __restrict__ WpF, const float* __restrict__ bp,
    u32* __restrict__ h_pack, u32* __restrict__ att_pack,
    const float* __restrict__ c_ws, u32* __restrict__ cnt, float* __restrict__ outp)
{
  __shared__ __align__(16) u32 hF[8192];     // 32KB: h fragments; re-used as att fragments during B phase
  __shared__ __align__(16) u32 xaH[4096];    // 16KB: score staging (8KB) / gates buffer (8.4KB), phase-aliased
  __shared__ __align__(16) u16 x_emL[16384]; // 32KB: step-invariant x_em[ba] staged ONCE ([e<256][p<64])
  __shared__ float gemA[256];     // g_em row for own batch (bias folded)
  __shared__ float wattA[256];
  __shared__ float bchA[256];
  __shared__ float alphaL[64];
  __shared__ float ptL[32*8];
  __shared__ float w5L[64*8];
  __shared__ float biasL[64];
  __shared__ float yL[32*33];     // head y staging (4.2KB)
  float* gbufL = (float*)xaH;
  float* stgL  = (float*)xaH;

  int t = threadIdx.x;
  int bg = blockIdx.x >> 5, gs = blockIdx.x & 31;
  int lane = t & 63, wv = t >> 6;
  int c0 = lane & 15, q = lane >> 4;

  // one-time staging
  wattA[t] = Watt[t];
  bchA[t]  = b_ch[t];
  if (t < 64){
    int grow = (t >> 4)*512 + gs*16 + (t & 15);
    biasL[t] = b_ih[grow] + b_hh[grow];
    #pragma unroll
    for (int d=0; d<5; ++d) w5L[t*8+d] = W_ih[grow*517 + 512 + d];
  }
  int bL = t & 31, hp = t >> 5;              // LSTM role
  int gb_l = bg*32 + bL;
  float c0r = c_ws[gb_l*512 + gs*16 + 2*hp];
  float c1r = c_ws[gb_l*512 + gs*16 + 2*hp + 1];
  int ba = bg*32 + gs;                       // own batch
  int mh_g = gs >> 4;                        // m-half holding our batch row
  int rq = (gs & 15) >> 2, rj = gs & 3;      // quad / reg of our row in the C-frag
  const u16* wb  = Wf   + (size_t)(((gs*4 + wv)*32)*64 + lane)*8;
  const u16* wcb = WcF2 + (size_t)((wv*4)*16*64 + lane)*8;   // g_em weight base for ni=0
  const u32* hsrc = h_pack + (size_t)bg*8192;
  const u32* asrc = att_pack + (size_t)bg*8192;
  int hpub_a = frag_a(bL, gs*8 + hp);        // h publish slot (fragment-major)
  int apub_a = ((gs>>4)<<12) + ((t>>4)<<8) + (((t>>2)&3)<<6) + ((gs&15)<<2) + (t&3);  // att publish slot
  // stage x_em[ba] (step-invariant, 32KB) into LDS: 8 x dwordx4 per thread, plain cached loads.
  // (round-3/4 post-mortem: this loop with i<16 overran x_emL by 32KB, clobbering gemA/wattA/bchA/
  //  w5L/biasL -> deterministic absmax 0.043 fail. 2048 u32x4 total / 256 threads = 8 per thread.)
  {
    const u32x4* xs = (const u32x4*)(x_em + (size_t)ba*16384);
    u32x4* xd = (u32x4*)x_emL;
    #pragma unroll
    for (int i=0;i<8;i++) xd[i*256 + t] = xs[i*256 + t];
  }
  // pre-stage pt for ts=0 (start token)
  if (t < 32){
    ptL[t*8+0]=0.f; ptL[t*8+1]=0.f; ptL[t*8+2]=1.f; ptL[t*8+3]=0.f; ptL[t*8+4]=0.f;
  }
  u32 seq = 0;
  __syncthreads();

  #pragma clang loop unroll(disable)
  for (int ts=0; ts<257; ++ts){
    // ======== stage h: batched coalesced agent-scope loads -> LDS (one latency epoch) ========
    stage32i(hF, hsrc, t);
    __syncthreads();
    // ======== A-gem: duplicated g_em GEMM (32x256x512), keep only own row ba ========
    {
      f32x4 ge0 = (f32x4)0.f, ge1 = (f32x4)0.f, ge2 = (f32x4)0.f, ge3 = (f32x4)0.f;
      #pragma unroll 4
      for (int ks=0; ks<16; ++ks){
        bf16x8 ahk = *(const bf16x8*)(&hF[(ks*2 + mh_g)*256 + lane*4]);
        bf16x8 b0 = as_bf8(*(const u32x4*)(const void*)(wcb + (size_t)(0*16 + ks)*512));
        bf16x8 b1 = as_bf8(*(const u32x4*)(const void*)(wcb + (size_t)(1*16 + ks)*512));
        bf16x8 b2 = as_bf8(*(const u32x4*)(const void*)(wcb + (size_t)(2*16 + ks)*512));
        bf16x8 b3 = as_bf8(*(const u32x4*)(const void*)(wcb + (size_t)(3*16 + ks)*512));
        ge0 = __builtin_amdgcn_mfma_f32_16x16x32_bf16(ahk, b0, ge0, 0,0,0);
        ge1 = __builtin_amdgcn_mfma_f32_16x16x32_bf16(ahk, b1, ge1, 0,0,0);
        ge2 = __builtin_amdgcn_mfma_f32_16x16x32_bf16(ahk, b2, ge2, 0,0,0);
        ge3 = __builtin_amdgcn_mfma_f32_16x16x32_bf16(ahk, b3, ge3, 0,0,0);
      }
      if (q == rq){
        gemA[(wv*4+0)*16 + c0] = ge0[rj] + bchA[(wv*4+0)*16 + c0];
        gemA[(wv*4+1)*16 + c0] = ge1[rj] + bchA[(wv*4+1)*16 + c0];
        gemA[(wv*4+2)*16 + c0] = ge2[rj] + bchA[(wv*4+2)*16 + c0];
        gemA[(wv*4+3)*16 + c0] = ge3[rj] + bchA[(wv*4+3)*16 + c0];
      }
    }
    __syncthreads();
    // ======== A-score: full 256-e scores for OWN batch from LDS x_em; thread=(e-group eg, p-octet ps) ========
    {
      int eg = t >> 3, ps = t & 7;
      float sp[8];
      #pragma unroll
      for (int j=0;j<8;j++) sp[j] = 0.f;
      const u16* xb = x_emL + (size_t)(eg*8)*64 + ps*8;
      #pragma unroll
      for (int e2=0; e2<8; ++e2){
        float gev = gemA[eg*8 + e2];
        float wev = wattA[eg*8 + e2];
        bf16x8 xv = *(const bf16x8*)(xb + (size_t)e2*64);
        #pragma unroll
        for (int j=0;j<8;j++)
          sp[j] += tanh_f(bf2f((u16)xv[j]) + gev) * wev;
      }
      #pragma unroll
      for (int j=0;j<8;j++) stgL[eg*64 + ps*8 + j] = sp[j];
    }
    __syncthreads();
    if (t < 64){
      float s = 0.f;
      #pragma unroll
      for (int g2=0; g2<32; ++g2) s += stgL[g2*64 + t];
      float m = s;
      #pragma unroll
      for (int d=1; d<64; d<<=1) m = fmaxf(m, __shfl_xor(m, d, 64));
      float ex = __builtin_amdgcn_exp2f((s - m) * L2E);
      float su = ex;
      #pragma unroll
      for (int d=1; d<64; d<<=1) su += __shfl_xor(su, d, 64);
      alphaL[t] = ex * __builtin_amdgcn_rcpf(su);
    }
    __syncthreads();
    {  // att[c] = sum_p alpha[p]*backbone[ba][c][p]; thread handles c = 2t, 2t+1
      const u16* base = bb_bf + (size_t)(ba*512 + 2*t)*64;
      float a0 = 0.f, a1 = 0.f;
      #pragma unroll
      for (int p8=0; p8<8; ++p8){
        bf16x8 v0 = *(const bf16x8*)(base + p8*8);
        bf16x8 v1 = *(const bf16x8*)(base + 64 + p8*8);
        #pragma unroll
        for (int j=0;j<8;j++){
          float al = alphaL[p8*8+j];
          a0 += al * bf2f((u16)v0[j]);
          a1 += al * bf2f((u16)v1[j]);
        }
      }
      sta(&att_pack[(size_t)bg*8192 + apub_a], packbf(a0, a1));
    }
    seq++; bar_arrive(cnt, bg, t);
    // ======== barrier-1 shadow: head C for step ts-1 (hF = h of iter ts-1), h-half gates ========
    if (gs < 4 && ts > 0){
      int mh = wv & 1, nt2 = wv >> 1;
      f32x4 ya = (f32x4)0.f;
      #pragma unroll 4
      for (int ks=0; ks<16; ++ks){
        bf16x8 bw = as_bf8(*(const u32x4*)(const void*)(WpF + (size_t)((((gs*2+nt2)*16 + ks)*64) + lane)*8));
        bf16x8 ah = *(const bf16x8*)(&hF[(ks*2 + mh)*256 + lane*4]);
        ya = __builtin_amdgcn_mfma_f32_16x16x32_bf16(ah, bw, ya, 0,0,0);
      }
      #pragma unroll
      for (int r=0;r<4;r++) yL[(mh*16 + q*4 + r)*33 + nt2*16 + c0] = ya[r];
      __syncthreads();
      if (wv == 3 && lane < 32) head_post(yL, bp, outp, gs, bg, lane, ts-1);
    }
    // h-half of gates (local hF only — no dependency on the att barrier)
    f32x4 acc0 = (f32x4)0.f, acc1 = (f32x4)0.f;
    #pragma unroll 4
    for (int ks2=0; ks2<16; ++ks2){
      bf16x8 bfr = as_bf8(*(const u32x4*)(const void*)(wb + (size_t)(16+ks2)*512));
      bf16x8 a0 = *(const bf16x8*)(&hF[(ks2*2)*256 + lane*4]);
      bf16x8 a1 = *(const bf16x8*)(&hF[(ks2*2+1)*256 + lane*4]);
      acc0 = __builtin_amdgcn_mfma_f32_16x16x32_bf16(a0, bfr, acc0, 0,0,0);
      acc1 = __builtin_amdgcn_mfma_f32_16x16x32_bf16(a1, bfr, acc1, 0,0,0);
    }
    bar_wait(cnt, bg, t, 32u*seq);
    // ======== B: stage FULL att (32KB, batched) into hF region; att-half gates; LSTM; publish h ========
    stage32i(hF, asrc, t);
    __syncthreads();
    #pragma unroll 4
    for (int kc=0; kc<16; ++kc){
      bf16x8 bfr = as_bf8(*(const u32x4*)(const void*)(wb + (size_t)kc*512));
      bf16x8 af0 = *(const bf16x8*)(&hF[kc*256 + lane*4]);
      bf16x8 af1 = *(const bf16x8*)(&hF[4096 + kc*256 + lane*4]);
      acc0 = __builtin_amdgcn_mfma_f32_16x16x32_bf16(af0, bfr, acc0, 0,0,0);
      acc1 = __builtin_amdgcn_mfma_f32_16x16x32_bf16(af1, bfr, acc1, 0,0,0);
    }
    {
      int n = wv*16 + c0;
      #pragma unroll
      for (int r=0;r<4;r++){
        gbufL[n*33 + (q*4 + r)]      = acc0[r];
        gbufL[n*33 + (16 + q*4 + r)] = acc1[r];
      }
    }
    __syncthreads();
    {
      float p0v = ptL[bL*8+0], p1v = ptL[bL*8+1], p2v = ptL[bL*8+2], p3v = ptL[bL*8+3], p4v = ptL[bL*8+4];
      auto gval = [&](int n)->float {
        return gbufL[n*33 + bL] + biasL[n]
             + p0v*w5L[n*8+0] + p1v*w5L[n*8+1] + p2v*w5L[n*8+2] + p3v*w5L[n*8+3] + p4v*w5L[n*8+4];
      };
      float hv0 = 0.f, hv1 = 0.f;
      #pragma unroll
      for (int k2=0;k2<2;k2++){
        int hh = 2*hp + k2;
        float gi = gval(hh), gf = gval(16+hh), gg = gval(32+hh), go = gval(48+hh);
        float cp = k2 ? c1r : c0r;
        float cn = sig_f(gf)*cp + sig_f(gi)*tanh_f(gg);
        float hv = sig_f(go)*tanh_f(cn);
        if (k2){ c1r = cn; hv1 = hv; } else { c0r = cn; hv0 = hv; }
      }
      sta(&h_pack[(size_t)bg*8192 + hpub_a], packbf(hv0, hv1));
    }
    seq++; bar_arrive(cnt, bg, t);
    // barrier-2 shadow: stage pt for step ts+1 (consumed only after next bar_wait's syncthreads)
    if (ts < 256 && t < 32){
      const float* sp = sketch + ((size_t)ts*256 + (bg*32 + t))*5;
      ptL[t*8+0]=sp[0]; ptL[t*8+1]=sp[1]; ptL[t*8+2]=sp[2]; ptL[t*8+3]=sp[3]; ptL[t*8+4]=sp[4];
    }
    bar_wait(cnt, bg, t, 32u*seq);
  }
  // ======== epilogue: head for step 256 (h_256 now in h_pack) ========
  if (gs < 4){
    stage32i(hF, hsrc, t);
    __syncthreads();
    int mh = wv & 1, nt2 = wv >> 1;
    f32x4 ya = (f32x4)0.f;
    #pragma unroll 4
    for (int ks=0; ks<16; ++ks){
      bf16x8 bw = as_bf8(*(const u32x4*)(const void*)(WpF + (size_t)((((gs*2+nt2)*16 + ks)*64) + lane)*8));
      bf16x8 ah = *(const bf16x8*)(&hF[(ks*2 + mh)*256 + lane*4]);
      ya = __builtin_amdgcn_mfma_f32_16x16x32_bf16(ah, bw, ya, 0,0,0);
    }
    #pragma unroll
    for (int r=0;r<4;r++) yL[(mh*16 + q*4 + r)*33 + nt2*16 + c0] = ya[r];
    __syncthreads();
    if (wv == 3 && lane < 32) head_post(yL, bp, outp, gs, bg, lane, 256);
  }
}

extern "C" void kernel_launch(void* const* d_in, const int* in_sizes, int n_in,
                              void* d_out, int out_size, void* d_ws, size_t ws_size,
                              hipStream_t stream){
  (void)in_sizes; (void)n_in; (void)out_size; (void)ws_size;
  const float* backbone = (const float*)d_in[0];
  const float* z_vec    = (const float*)d_in[1];
  const float* sketch   = (const float*)d_in[2];
  const float* W_fc_hc  = (const float*)d_in[3];
  const float* b_fc_hc  = (const float*)d_in[4];
  const float* W_conv_h = (const float*)d_in[5];
  const float* b_conv_h = (const float*)d_in[6];
  const float* K_conv_f = (const float*)d_in[7];
  const float* b_conv_f = (const float*)d_in[8];
  const float* W_att    = (const float*)d_in[9];
  // d_in[10] = b_conv_att: additive constant to all scores -> softmax-invariant, skipped
  const float* W_ih     = (const float*)d_in[11];
  const float* W_hh     = (const float*)d_in[12];
  const float* b_ih     = (const float*)d_in[13];
  const float* b_hh     = (const float*)d_in[14];
  const float* W_fcp    = (const float*)d_in[15];
  const float* b_fcp    = (const float*)d_in[16];

  char* ws = (char*)d_ws;
  u32*   cnt      = (u32*)(ws + 0);              // 16,384 (8 counters, 128B apart)
  u32*   h_pack   = (u32*)(ws + 16384);          // 262,144 (fragment-major per bg)
  u32*   att_pack = (u32*)(ws + 278528);         // 262,144 (fragment-major per bg)
  float* c_ws     = (float*)(ws + 2637824);      // 524,288
  u16*   x_em     = (u16*)(ws + 3162112);        // 8,388,608
  u16*   Wf       = (u16*)(ws + 11550720);       // 4,194,304
  u16*   Kf       = (u16*)(ws + 15745024);       // 2,359,296
  u16*   WcF2     = (u16*)(ws + 18104320);       // 262,144
  u16*   WpF      = (u16*)(ws + 18628608);       // 131,072
  u16*   bb_bf    = (u16*)(ws + 18759680);       // 4,194,304

  (void)hipMemsetAsync(cnt, 0, 16384, stream);
  k_prep_w  <<<8192, 256, 0, stream>>>(W_ih, W_hh, Wf);
  k_prep_kf <<<4608, 256, 0, stream>>>(K_conv_f, Kf);
  k_prep_wcf2<<<512, 256, 0, stream>>>(W_conv_h, WcF2);
  k_prep_wp <<<256,  256, 0, stream>>>(W_fcp, WpF);
  k_hc      <<<256,  256, 0, stream>>>(z_vec, W_fc_hc, b_fc_hc, h_pack, c_ws);
  k_conv    <<<256,  256, 0, stream>>>(backbone, Kf, b_conv_f, x_em, bb_bf);
  k_rnn     <<<256,  256, 0, stream>>>(bb_bf, sketch, b_conv_h, W_att, W_ih, b_ih, b_hh,
                                       x_em, Wf, WcF2, WpF, b_fcp,
                                       h_pack, att_pack, c_ws, cnt, (float*)d_out);
}

// Round 6
// 4547.173 us; speedup vs baseline: 2.9048x; 1.3310x over previous
//
#include <hip/hip_runtime.h>
#include <hip/hip_bf16.h>

typedef unsigned short u16;
typedef unsigned int   u32;
typedef unsigned long long u64;

typedef __attribute__((ext_vector_type(8))) short bf16x8;  // 8 x bf16 (4 VGPR) MFMA A/B frag
typedef __attribute__((ext_vector_type(4))) float f32x4;   // MFMA C/D frag
typedef __attribute__((ext_vector_type(4))) u32   u32x4;

#define L2E 1.44269504088896340736f

__device__ __forceinline__ float bf2f(u16 u){ union{u32 i; float f;} v; v.i=((u32)u)<<16; return v.f; }
__device__ __forceinline__ u16  f2bf(float f){ union{float f; u32 i;} v; v.f=f; u32 u=v.i; return (u16)((u + 0x7fffu + ((u>>16)&1u))>>16); }
__device__ __forceinline__ u32  packbf(float a,float b){ return (u32)f2bf(a) | ((u32)f2bf(b)<<16); }
__device__ __forceinline__ float tanh_f(float x){
  float cx = fminf(fmaxf(x,-15.f),15.f);
  float e  = __builtin_amdgcn_exp2f(cx*(2.f*L2E));
  return (e-1.f)*__builtin_amdgcn_rcpf(e+1.f);
}
__device__ __forceinline__ float sig_f(float x){
  float cx = fminf(fmaxf(x,-30.f),30.f);
  float e  = __builtin_amdgcn_exp2f(-cx*L2E);
  return __builtin_amdgcn_rcpf(1.f+e);
}
// Cross-XCD coherent accesses: relaxed agent-scope atomics (bypass per-XCD caches; L3 = coherence point).
__device__ __forceinline__ u64   lda2(const u64* p){ return __hip_atomic_load((u64*)p, __ATOMIC_RELAXED, __HIP_MEMORY_SCOPE_AGENT); }
__device__ __forceinline__ u32   lda1(const u32* p){ return __hip_atomic_load((u32*)p, __ATOMIC_RELAXED, __HIP_MEMORY_SCOPE_AGENT); }
__device__ __forceinline__ void  sta(u32* p, u32 v){ __hip_atomic_store(p, v, __ATOMIC_RELAXED, __HIP_MEMORY_SCOPE_AGENT); }
__device__ __forceinline__ bf16x8 as_bf8(u32x4 w){ union{u32x4 u; bf16x8 b;} c; c.u=w; return c.b; }
// fragment-major address for an h/att element pair: batch r, u32-col c (h element pair 2c,2c+1)
__device__ __forceinline__ int frag_a(int r, int c){
  return ((c>>4)*2 + (r>>4))*256 + (((c>>2)&3))*64 + ((r&15))*4 + (c&3);
}

// ---- batched 32KB L3->LDS stage: 16 independent agent-scope u64 loads into registers (all in flight),
// then 16 ds_write_b64. One latency epoch instead of 16 serial round trips. ----
__device__ __forceinline__ void stage32i(u32* lds, const u32* gsrc, int t){
  const u64* g = (const u64*)gsrc;
  u64* d = (u64*)lds;
  u64 r[16];
  #pragma unroll
  for (int k=0;k<16;k++) r[k] = lda2(&g[k*256 + t]);
  #pragma unroll
  for (int k=0;k<16;k++) d[k*256 + t] = r[k];
}

// ---------------- prep: W_ih/W_hh (f32) -> fragment-major bf16 Wf [gs][nt<4][ks<32][lane][8] ----------------
__global__ void k_prep_w(const float* __restrict__ W_ih, const float* __restrict__ W_hh, u16* __restrict__ Wf){
  int idx = blockIdx.x*256 + threadIdx.x;        // 2,097,152
  int j    = idx & 7;
  int lane = (idx >> 3) & 63;
  int ks   = (idx >> 9) & 31;
  int nt   = (idx >> 14) & 3;
  int gs   = idx >> 16;                          // < 32
  int grow = nt*512 + gs*16 + (lane & 15);       // global gate row (nt = gate i/f/g/o)
  int k    = ks*32 + ((lane >> 4) & 3)*8 + j;    // 0..1023: [att 512 | h 512]
  float v = (k < 512) ? W_ih[grow*517 + k] : W_hh[grow*512 + (k - 512)];
  Wf[idx] = f2bf(v);
}
// ---------------- prep: K_conv (f32) -> fragment-major bf16 Kf [tap][nt<16][ks<16][lane][8] ----------------
__global__ void k_prep_kf(const float* __restrict__ Kc, u16* __restrict__ Kf){
  int idx = blockIdx.x*256 + threadIdx.x;        // 1,179,648
  int j    = idx & 7;
  int lane = (idx >> 3) & 63;
  int ks   = (idx >> 9) & 15;
  int nt   = (idx >> 13) & 15;
  int tap  = idx >> 17;                          // < 9
  int oc = nt*16 + (lane & 15);
  int ic = ks*32 + ((lane >> 4) & 3)*8 + j;
  Kf[idx] = f2bf(Kc[(oc*512 + ic)*9 + tap]);
}
// ---------------- prep: W_conv_h (f32) -> FULL fragment-major bf16 WcF2 [nt<16][ks<16][lane][8] ----------------
__global__ void k_prep_wcf2(const float* __restrict__ Wch, u16* __restrict__ WcF2){
  int idx = blockIdx.x*256 + threadIdx.x;        // 131,072
  int j = idx & 7, lane = (idx>>3) & 63, ks = (idx>>9) & 15, nt = idx >> 13;   // nt<16
  int e = nt*16 + (lane & 15);
  int k = ks*32 + ((lane >> 4) & 3)*8 + j;
  WcF2[idx] = f2bf(Wch[e*512 + k]);
}
// ---------------- prep: W_fc_params (f32) -> fragment-major bf16 WpF [ntile<8][ks<16][lane][8] ----------------
__global__ void k_prep_wp(const float* __restrict__ Wp, u16* __restrict__ WpF){
  int idx = blockIdx.x*256 + threadIdx.x;        // 65,536
  int j = idx & 7, lane = (idx>>3) & 63, ks = (idx>>9) & 15, ntile = idx >> 13;
  int n = ntile*16 + (lane & 15);
  int k = ks*32 + (lane >> 4)*8 + j;
  WpF[idx] = (n < 123) ? f2bf(Wp[n*512 + k]) : (u16)0;
}
// ---------------- init: hc = tanh(z @ W_fc_hc^T + b) -> h_pack (fragment-major bf16 pairs), c_ws (f32) ----------------
__global__ void k_hc(const float* __restrict__ z, const float* __restrict__ Wfc, const float* __restrict__ bfc,
                     u32* __restrict__ h_pack, float* __restrict__ c_ws){
  __shared__ float zl[128];
  int b = blockIdx.x, t = threadIdx.x;
  if (t < 128) zl[t] = z[b*128 + t];
  __syncthreads();
  float acc[4];
  #pragma unroll
  for (int i=0;i<4;i++){
    int n = 4*t + i;
    const float* row = Wfc + n*128;
    float a = 0.f;
    #pragma unroll 8
    for (int k2=0;k2<128;k2++) a += row[k2]*zl[k2];
    acc[i] = tanh_f(a + bfc[n]);
  }
  int bg = b >> 5, r = b & 31;
  if (t < 128){
    h_pack[bg*8192 + frag_a(r, 2*t)]   = packbf(acc[0], acc[1]);
    h_pack[bg*8192 + frag_a(r, 2*t+1)] = packbf(acc[2], acc[3]);
  } else {
    int base = 4*t - 512;
    #pragma unroll
    for (int i=0;i<4;i++) c_ws[b*512 + base + i] = acc[i];
  }
}
// ---------------- conv 3x3 SAME (f32 in, bf16 out) + bf16 backbone copy ----------------
__device__ __forceinline__ int xt_addr(int p, int chunk){ return p*512 + ((chunk ^ (p & 7))<<3); } // XOR-swizzled LDS
__global__ __launch_bounds__(256) void k_conv(const float* __restrict__ bb, const u16* __restrict__ Kf,
                       const float* __restrict__ bcf, u16* __restrict__ x_em, u16* __restrict__ bb_bf){
  __shared__ u16 xt[64*512];  // exactly 64KB, swizzled [p][ic]
  int b = blockIdx.x, t = threadIdx.x;
  const float* src = bb + (size_t)b*512*64;
  u16* dstc = bb_bf + (size_t)b*512*64;
  for (int i=0;i<128;i++){
    int idx = i*256 + t;
    int ic = idx >> 6, p = idx & 63;
    u16 v = f2bf(src[idx]);
    xt[xt_addr(p, ic>>3) + (ic&7)] = v;
    dstc[idx] = v;                         // bf16 copy, same [b][c][p] layout
  }
  __syncthreads();
  int wv = t >> 6, l = t & 63, c0 = l & 15, q = l >> 4;
  f32x4 acc[4][4];
  #pragma unroll
  for (int a=0;a<4;a++)
    #pragma unroll
    for (int bq=0;bq<4;bq++) acc[a][bq] = (f32x4)0.f;
  for (int tap=0; tap<9; ++tap){
    int ty = tap/3 - 1, tx = tap%3 - 1;
    for (int ks=0; ks<16; ++ks){
      bf16x8 afr[4];
      #pragma unroll
      for (int mt=0; mt<4; ++mt){
        int p = mt*16 + c0;
        int py = (p >> 3) + ty, px = (p & 7) + tx;
        if ((unsigned)py < 8u && (unsigned)px < 8u){
          afr[mt] = *(const bf16x8*)(&xt[xt_addr(py*8+px, ks*4 + q)]);
        } else {
          afr[mt] = (bf16x8)0;
        }
      }
      #pragma unroll
      for (int ni=0; ni<4; ++ni){
        int nt = wv*4 + ni;
        bf16x8 bfr = as_bf8(*(const u32x4*)(const void*)(Kf + (size_t)((((tap*16 + nt)*16 + ks)*64) + l)*8));
        #pragma unroll
        for (int mt=0; mt<4; ++mt)
          acc[mt][ni] = __builtin_amdgcn_mfma_f32_16x16x32_bf16(afr[mt], bfr, acc[mt][ni], 0,0,0);
      }
    }
  }
  #pragma unroll
  for (int ni=0; ni<4; ++ni){
    int e = (wv*4+ni)*16 + c0;
    float bias = bcf[e];
    #pragma unroll
    for (int mt=0; mt<4; ++mt)
      #pragma unroll
      for (int r=0;r<4;r++){
        int p = mt*16 + q*4 + r;
        x_em[(size_t)(b*256 + e)*64 + p] = f2bf(acc[mt][ni][r] + bias);
      }
  }
}

// ---------------- flag-array barrier: NO atomic RMW (32 plain relaxed stores to distinct 4B slots =
// 2 cache lines per bg; no same-line RMW serialization at L3), wave-parallel coalesced ballot poll
// (each of lanes 0..31 watches one flag; one L3 trip checks all 32; every wave exits autonomously).
// Data ordering: __syncthreads in arrive drains vmcnt(0) so all agent-scope data stores are at the
// coherence point before the flag store issues; acquire signal-fence keeps data loads after the poll. ----
__device__ __forceinline__ void bar_arrive(u32* flags, int bg, int gs, int t, u32 seq){
  __syncthreads();   // all waves' agent-scope data stores acked at coherence point
  if (t == 0) sta(&flags[bg*64 + gs], seq);
}
__device__ __forceinline__ void bar_wait(u32* flags, int bg, int lane, u32 seq){
  const u32* f = &flags[bg*64 + (lane & 31)];
  for (;;){
    u32 v = lda1(f);
    if (__ballot(v < seq) == 0ull) break;
    __builtin_amdgcn_s_sleep(2);
  }
  __atomic_signal_fence(__ATOMIC_ACQUIRE);   // compiler barrier only: data loads stay after the spin
}

// ---------------- head postprocess, parallelized over all 256 threads ----------------
__device__ __forceinline__ void head_post_par(const float* yL, const float* __restrict__ bp,
                                              float* __restrict__ out, float* mrsL,
                                              int gs, int bg, int t, int step){
  const int CH = 1315840;          // 65792*20
  const int PEN = 7895040;         // 6*CH
  // phase 1: pen softmax scalars (cols 3..22 live in gs==0's 32-col tile); one lane per batch
  if (gs == 0 && t < 32){
    float m = -1e30f;
    #pragma unroll 1
    for (int c=3;c<23;c++){ float v = yL[t*33 + c] + bp[c]; m = fmaxf(m, v); }
    float su = 0.f;
    #pragma unroll 1
    for (int c=3;c<23;c++){ float v = yL[t*33 + c] + bp[c]; su += __builtin_amdgcn_exp2f((v-m)*L2E); }
    mrsL[t*2]   = m;
    mrsL[t*2+1] = __builtin_amdgcn_rcpf(su);
  }
  __syncthreads();
  // phase 2: all 256 threads: batch b = t>>3, 4 cols each
  int b = t >> 3, cb = (t & 7)*4;
  float m = mrsL[b*2], rs = mrsL[b*2+1];
  int rr = (bg*32 + b)*257 + step;
  #pragma unroll
  for (int i=0;i<4;i++){
    int c2 = cb + i;
    int col = gs*32 + c2;
    if (col >= 123) break;
    float v = yL[b*33 + c2] + bp[col];
    float tv; int oidx;
    if (col < 3){ tv = v; oidx = PEN + rr*3 + col; }
    else {
      int j = col - 3, ch = j/20, jj = j - ch*20;
      if (ch == 0)      tv = __builtin_amdgcn_exp2f((v-m)*L2E)*rs;
      else if (ch <= 2) tv = v;
      else if (ch <= 4) tv = __builtin_amdgcn_exp2f(v*L2E);
      else              tv = tanh_f(v);
      oidx = ch*CH + rr*20 + jj;
    }
    __builtin_nontemporal_store(tv, &out[oidx]);
  }
}

// ---------------- persistent RNN scan + fused head: 8 bg-groups x 32 gs-blocks, 2 barriers/step ----------------
__global__ __launch_bounds__(256) void k_rnn(
    const u16* __restrict__ bb_bf, const float* __restrict__ sketch,
    const float* __restrict__ b_ch, const float* __restrict__ Watt,
    const float* __restrict__ W_ih, const float* __restrict__ b_ih, const float* __restrict__ b_hh,
    const u16* __restrict__ x_em, const u16* __restrict__ Wf, const u16* __restrict__ WcF2,
    const u16* __restrict__ WpF, const float* __restrict__ bp,
    u32* __restrict__ h_pack, u32* __restrict__ att_pack,
    const float* __restrict__ c_ws, u32* __restrict__ flags, float* __restrict__ outp)
{
  __shared__ __align__(16) u32 hF[8192];     // 32KB: h fragments, valid the whole iteration
  __shared__ __align__(16) u32 attF[8192];   // 32KB: att fragments (own buffer -> hF survives for head C)
  __shared__ __align__(16) u32 xaH[4096];    // 16KB: score staging (8KB) / gates buffer (8.4KB), phase-aliased
  __shared__ __align__(16) u16 x_emL[16384]; // 32KB: step-invariant x_em[ba] staged ONCE ([e<256][p<64])
  __shared__ float gemA[256];     // g_em row for own batch (bias folded)
  __shared__ float wattA[256];
  __shared__ float bchA[256];
  __shared__ float alphaL[64];
  __shared__ float ptL[32*8];
  __shared__ float w5L[64*8];
  __shared__ float biasL[64];
  __shared__ float yL[32*33];     // head y staging (4.2KB)
  __shared__ float mrsL[64];
  float* gbufL = (float*)xaH;
  float* stgL  = (float*)xaH;

  int t = threadIdx.x;
  int bg = blockIdx.x >> 5, gs = blockIdx.x & 31;
  int lane = t & 63, wv = t >> 6;
  int c0 = lane & 15, q = lane >> 4;

  // one-time staging
  wattA[t] = Watt[t];
  bchA[t]  = b_ch[t];
  if (t < 64){
    int grow = (t >> 4)*512 + gs*16 + (t & 15);
    biasL[t] = b_ih[grow] + b_hh[grow];
    #pragma unroll
    for (int d=0; d<5; ++d) w5L[t*8+d] = W_ih[grow*517 + 512 + d];
  }
  int bL = t & 31, hp = t >> 5;              // LSTM role
  int gb_l = bg*32 + bL;
  float c0r = c_ws[gb_l*512 + gs*16 + 2*hp];
  float c1r = c_ws[gb_l*512 + gs*16 + 2*hp + 1];
  int ba = bg*32 + gs;                       // own batch
  int mh_g = gs >> 4;                        // m-half holding our batch row
  int rq = (gs & 15) >> 2, rj = gs & 3;      // quad / reg of our row in the C-frag
  const u16* wb  = Wf   + (size_t)(((gs*4 + wv)*32)*64 + lane)*8;
  const u16* wcb = WcF2 + (size_t)((wv*4)*16*64 + lane)*8;   // g_em weight base for ni=0
  const u32* hsrc = h_pack + (size_t)bg*8192;
  const u32* asrc = att_pack + (size_t)bg*8192;
  int hpub_a = frag_a(bL, gs*8 + hp);        // h publish slot (fragment-major)
  int apub_a = ((gs>>4)<<12) + ((t>>4)<<8) + (((t>>2)&3)<<6) + ((gs&15)<<2) + (t&3);  // att publish slot
  // stage x_em[ba] (step-invariant, 32KB = 2048 u32x4) into LDS: 8 per thread (bounds-checked!)
  {
    const u32x4* xs = (const u32x4*)(x_em + (size_t)ba*16384);
    u32x4* xd = (u32x4*)x_emL;
    #pragma unroll
    for (int i=0;i<8;i++) xd[i*256 + t] = xs[i*256 + t];
  }
  // pre-stage pt for ts=0 (start token)
  if (t < 32){
    ptL[t*8+0]=0.f; ptL[t*8+1]=0.f; ptL[t*8+2]=1.f; ptL[t*8+3]=0.f; ptL[t*8+4]=0.f;
  }
  u32 seq = 0;
  __syncthreads();

  #pragma clang loop unroll(disable)
  for (int ts=0; ts<257; ++ts){
    // guard hF WAR: head C (bar2 shadow of prev iter) read hF; all waves passed bar2-wait
    __syncthreads();
    // ======== stage h: batched coalesced agent-scope loads -> LDS (one latency epoch) ========
    stage32i(hF, hsrc, t);
    __syncthreads();
    // ======== A-gem: duplicated g_em GEMM (32x256x512), keep only own row ba ========
    {
      f32x4 ge0 = (f32x4)0.f, ge1 = (f32x4)0.f, ge2 = (f32x4)0.f, ge3 = (f32x4)0.f;
      #pragma unroll 8
      for (int ks=0; ks<16; ++ks){
        bf16x8 ahk = *(const bf16x8*)(&hF[(ks*2 + mh_g)*256 + lane*4]);
        bf16x8 b0 = as_bf8(*(const u32x4*)(const void*)(wcb + (size_t)(0*16 + ks)*512));
        bf16x8 b1 = as_bf8(*(const u32x4*)(const void*)(wcb + (size_t)(1*16 + ks)*512));
        bf16x8 b2 = as_bf8(*(const u32x4*)(const void*)(wcb + (size_t)(2*16 + ks)*512));
        bf16x8 b3 = as_bf8(*(const u32x4*)(const void*)(wcb + (size_t)(3*16 + ks)*512));
        ge0 = __builtin_amdgcn_mfma_f32_16x16x32_bf16(ahk, b0, ge0, 0,0,0);
        ge1 = __builtin_amdgcn_mfma_f32_16x16x32_bf16(ahk, b1, ge1, 0,0,0);
        ge2 = __builtin_amdgcn_mfma_f32_16x16x32_bf16(ahk, b2, ge2, 0,0,0);
        ge3 = __builtin_amdgcn_mfma_f32_16x16x32_bf16(ahk, b3, ge3, 0,0,0);
      }
      if (q == rq){
        gemA[(wv*4+0)*16 + c0] = ge0[rj] + bchA[(wv*4+0)*16 + c0];
        gemA[(wv*4+1)*16 + c0] = ge1[rj] + bchA[(wv*4+1)*16 + c0];
        gemA[(wv*4+2)*16 + c0] = ge2[rj] + bchA[(wv*4+2)*16 + c0];
        gemA[(wv*4+3)*16 + c0] = ge3[rj] + bchA[(wv*4+3)*16 + c0];
      }
    }
    __syncthreads();
    // ======== A-score: full 256-e scores for OWN batch from LDS x_em; thread=(e-group eg, p-octet ps) ========
    {
      int eg = t >> 3, ps = t & 7;
      float sp[8];
      #pragma unroll
      for (int j=0;j<8;j++) sp[j] = 0.f;
      const u16* xb = x_emL + (size_t)(eg*8)*64 + ps*8;
      #pragma unroll
      for (int e2=0; e2<8; ++e2){
        float gev = gemA[eg*8 + e2];
        float wev = wattA[eg*8 + e2];
        bf16x8 xv = *(const bf16x8*)(xb + (size_t)e2*64);
        #pragma unroll
        for (int j=0;j<8;j++)
          sp[j] += tanh_f(bf2f((u16)xv[j]) + gev) * wev;
      }
      #pragma unroll
      for (int j=0;j<8;j++) stgL[eg*64 + ps*8 + j] = sp[j];
    }
    __syncthreads();
    if (t < 64){
      float s = 0.f;
      #pragma unroll
      for (int g2=0; g2<32; ++g2) s += stgL[g2*64 + t];
      float m = s;
      #pragma unroll
      for (int d=1; d<64; d<<=1) m = fmaxf(m, __shfl_xor(m, d, 64));
      float ex = __builtin_amdgcn_exp2f((s - m) * L2E);
      float su = ex;
      #pragma unroll
      for (int d=1; d<64; d<<=1) su += __shfl_xor(su, d, 64);
      alphaL[t] = ex * __builtin_amdgcn_rcpf(su);
    }
    __syncthreads();
    {  // att[c] = sum_p alpha[p]*backbone[ba][c][p]; thread handles c = 2t, 2t+1
      const u16* base = bb_bf + (size_t)(ba*512 + 2*t)*64;
      float a0 = 0.f, a1 = 0.f;
      #pragma unroll
      for (int p8=0; p8<8; ++p8){
        bf16x8 v0 = *(const bf16x8*)(base + p8*8);
        bf16x8 v1 = *(const bf16x8*)(base + 64 + p8*8);
        #pragma unroll
        for (int j=0;j<8;j++){
          float al = alphaL[p8*8+j];
          a0 += al * bf2f((u16)v0[j]);
          a1 += al * bf2f((u16)v1[j]);
        }
      }
      sta(&att_pack[(size_t)bg*8192 + apub_a], packbf(a0, a1));
    }
    seq++; bar_arrive(flags, bg, gs, t, seq);
    // ======== barrier-1 shadow: h-half gates (local hF only — no dependency on the att barrier) ========
    f32x4 acc0 = (f32x4)0.f, acc1 = (f32x4)0.f;
    #pragma unroll 8
    for (int ks2=0; ks2<16; ++ks2){
      bf16x8 bfr = as_bf8(*(const u32x4*)(const void*)(wb + (size_t)(16+ks2)*512));
      bf16x8 a0 = *(const bf16x8*)(&hF[(ks2*2)*256 + lane*4]);
      bf16x8 a1 = *(const bf16x8*)(&hF[(ks2*2+1)*256 + lane*4]);
      acc0 = __builtin_amdgcn_mfma_f32_16x16x32_bf16(a0, bfr, acc0, 0,0,0);
      acc1 = __builtin_amdgcn_mfma_f32_16x16x32_bf16(a1, bfr, acc1, 0,0,0);
    }
    bar_wait(flags, bg, lane, seq);
    // ======== B: stage FULL att (32KB, batched) into attF; att-half gates; LSTM; publish h ========
    stage32i(attF, asrc, t);
    __syncthreads();
    #pragma unroll 8
    for (int kc=0; kc<16; ++kc){
      bf16x8 bfr = as_bf8(*(const u32x4*)(const void*)(wb + (size_t)kc*512));
      bf16x8 af0 = *(const bf16x8*)(&attF[kc*256 + lane*4]);
      bf16x8 af1 = *(const bf16x8*)(&attF[4096 + kc*256 + lane*4]);
      acc0 = __builtin_amdgcn_mfma_f32_16x16x32_bf16(af0, bfr, acc0, 0,0,0);
      acc1 = __builtin_amdgcn_mfma_f32_16x16x32_bf16(af1, bfr, acc1, 0,0,0);
    }
    {
      int n = wv*16 + c0;
      #pragma unroll
      for (int r=0;r<4;r++){
        gbufL[n*33 + (q*4 + r)]      = acc0[r];
        gbufL[n*33 + (16 + q*4 + r)] = acc1[r];
      }
    }
    __syncthreads();
    {
      float p0v = ptL[bL*8+0], p1v = ptL[bL*8+1], p2v = ptL[bL*8+2], p3v = ptL[bL*8+3], p4v = ptL[bL*8+4];
      auto gval = [&](int n)->float {
        return gbufL[n*33 + bL] + biasL[n]
             + p0v*w5L[n*8+0] + p1v*w5L[n*8+1] + p2v*w5L[n*8+2] + p3v*w5L[n*8+3] + p4v*w5L[n*8+4];
      };
      float hv0 = 0.f, hv1 = 0.f;
      #pragma unroll
      for (int k2=0;k2<2;k2++){
        int hh = 2*hp + k2;
        float gi = gval(hh), gf = gval(16+hh), gg = gval(32+hh), go = gval(48+hh);
        float cp = k2 ? c1r : c0r;
        float cn = sig_f(gf)*cp + sig_f(gi)*tanh_f(gg);
        float hv = sig_f(go)*tanh_f(cn);
        if (k2){ c1r = cn; hv1 = hv; } else { c0r = cn; hv0 = hv; }
      }
      sta(&h_pack[(size_t)bg*8192 + hpub_a], packbf(hv0, hv1));
    }
    seq++; bar_arrive(flags, bg, gs, t, seq);
    // ======== barrier-2 shadow: pt for ts+1; head C for output step ts-1 (hF still = h_{ts-1}) ========
    if (ts < 256 && t < 32){
      const float* sp = sketch + ((size_t)ts*256 + (bg*32 + t))*5;
      ptL[t*8+0]=sp[0]; ptL[t*8+1]=sp[1]; ptL[t*8+2]=sp[2]; ptL[t*8+3]=sp[3]; ptL[t*8+4]=sp[4];
    }
    if (gs < 4 && ts > 0){
      int mh = wv & 1, nt2 = wv >> 1;
      f32x4 ya = (f32x4)0.f;
      #pragma unroll 8
      for (int ks=0; ks<16; ++ks){
        bf16x8 bw = as_bf8(*(const u32x4*)(const void*)(WpF + (size_t)((((gs*2+nt2)*16 + ks)*64) + lane)*8));
        bf16x8 ah = *(const bf16x8*)(&hF[(ks*2 + mh)*256 + lane*4]);
        ya = __builtin_amdgcn_mfma_f32_16x16x32_bf16(ah, bw, ya, 0,0,0);
      }
      #pragma unroll
      for (int r=0;r<4;r++) yL[(mh*16 + q*4 + r)*33 + nt2*16 + c0] = ya[r];
      __syncthreads();
      head_post_par(yL, bp, outp, mrsL, gs, bg, t, ts-1);
    }
    bar_wait(flags, bg, lane, seq);
  }
  // ======== epilogue: head for step 256 (h_256 now in h_pack) ========
  if (gs < 4){
    __syncthreads();
    stage32i(hF, hsrc, t);
    __syncthreads();
    int mh = wv & 1, nt2 = wv >> 1;
    f32x4 ya = (f32x4)0.f;
    #pragma unroll 8
    for (int ks=0; ks<16; ++ks){
      bf16x8 bw = as_bf8(*(const u32x4*)(const void*)(WpF + (size_t)((((gs*2+nt2)*16 + ks)*64) + lane)*8));
      bf16x8 ah = *(const bf16x8*)(&hF[(ks*2 + mh)*256 + lane*4]);
      ya = __builtin_amdgcn_mfma_f32_16x16x32_bf16(ah, bw, ya, 0,0,0);
    }
    #pragma unroll
    for (int r=0;r<4;r++) yL[(mh*16 + q*4 + r)*33 + nt2*16 + c0] = ya[r];
    __syncthreads();
    head_post_par(yL, bp, outp, mrsL, gs, bg, t, 256);
  }
}

extern "C" void kernel_launch(void* const* d_in, const int* in_sizes, int n_in,
                              void* d_out, int out_size, void* d_ws, size_t ws_size,
                              hipStream_t stream){
  (void)in_sizes; (void)n_in; (void)out_size; (void)ws_size;
  const float* backbone = (const float*)d_in[0];
  const float* z_vec    = (const float*)d_in[1];
  const float* sketch   = (const float*)d_in[2];
  const float* W_fc_hc  = (const float*)d_in[3];
  const float* b_fc_hc  = (const float*)d_in[4];
  const float* W_conv_h = (const float*)d_in[5];
  const float* b_conv_h = (const float*)d_in[6];
  const float* K_conv_f = (const float*)d_in[7];
  const float* b_conv_f = (const float*)d_in[8];
  const float* W_att    = (const float*)d_in[9];
  // d_in[10] = b_conv_att: additive constant to all scores -> softmax-invariant, skipped
  const float* W_ih     = (const float*)d_in[11];
  const float* W_hh     = (const float*)d_in[12];
  const float* b_ih     = (const float*)d_in[13];
  const float* b_hh     = (const float*)d_in[14];
  const float* W_fcp    = (const float*)d_in[15];
  const float* b_fcp    = (const float*)d_in[16];

  char* ws = (char*)d_ws;
  u32*   flags    = (u32*)(ws + 0);              // 16,384 (8 bg x 32 flags, 4B stride)
  u32*   h_pack   = (u32*)(ws + 16384);          // 262,144 (fragment-major per bg)
  u32*   att_pack = (u32*)(ws + 278528);         // 262,144 (fragment-major per bg)
  float* c_ws     = (float*)(ws + 2637824);      // 524,288
  u16*   x_em     = (u16*)(ws + 3162112);        // 8,388,608
  u16*   Wf       = (u16*)(ws + 11550720);       // 4,194,304
  u16*   Kf       = (u16*)(ws + 15745024);       // 2,359,296
  u16*   WcF2     = (u16*)(ws + 18104320);       // 262,144
  u16*   WpF      = (u16*)(ws + 18628608);       // 131,072
  u16*   bb_bf    = (u16*)(ws + 18759680);       // 4,194,304

  (void)hipMemsetAsync(flags, 0, 16384, stream);
  k_prep_w  <<<8192, 256, 0, stream>>>(W_ih, W_hh, Wf);
  k_prep_kf <<<4608, 256, 0, stream>>>(K_conv_f, Kf);
  k_prep_wcf2<<<512, 256, 0, stream>>>(W_conv_h, WcF2);
  k_prep_wp <<<256,  256, 0, stream>>>(W_fcp, WpF);
  k_hc      <<<256,  256, 0, stream>>>(z_vec, W_fc_hc, b_fc_hc, h_pack, c_ws);
  k_conv    <<<256,  256, 0, stream>>>(backbone, Kf, b_conv_f, x_em, bb_bf);
  k_rnn     <<<256,  256, 0, stream>>>(bb_bf, sketch, b_conv_h, W_att, W_ih, b_ih, b_hh,
                                       x_em, Wf, WcF2, WpF, b_fcp,
                                       h_pack, att_pack, c_ws, flags, (float*)d_out);
}